// Round 11
// baseline (494.486 us; speedup 1.0000x reference)
//
#include <hip/hip_runtime.h>
#include <hip/hip_bf16.h>

namespace {
constexpr int kB = 4;
constexpr int kC = 512;
constexpr int kH = 128;
constexpr int kW = 128;
constexpr int kCQK = 64;
constexpr int kL = kH * kW;   // 16384
constexpr int kO = 640;       // rows: [0,64)=Wq, [64,128)=Wk, [128,640)=Wv

// workspace layout (float offsets)
constexpr size_t OFF_WALL = 0;                          // wpk: 640*512*2 bf16
constexpr size_t OFF_BALL = (size_t)kO * kC;            // 640
constexpr size_t OFF_QKV  = OFF_BALL + kO;              // B*640*L region
constexpr size_t OFF_E    = OFF_QKV + (size_t)kB * kO * kL;  // B*H*W*256 fp32
constexpr size_t WS_FLOATS = OFF_E + (size_t)kB * kH * kW * 256;
// Per-batch q/k region (first 128 fp32-rows = 8.4MB/b):
//   proj writes qkb bf16 planes (u16 offsets): qh@0, ql@1M, kh@2M, kl@3M
//   escore reads qkb; softmax overwrites with afrag[0,2M) + arowT[2M,4M)
// Per-batch v region (rows 128..640 of old fp32 layout, 33.5MB/b):
//   proj writes vbf[c 512][l 16384] bf16 into the FRONT 16.8MB; back half unused.
// e region (67MB): xpk (pre-proj) -> scores fp32 -> vfrag bf16

typedef __attribute__((ext_vector_type(8))) short bf16x8;
typedef __attribute__((ext_vector_type(4))) float f32x4;

__device__ __forceinline__ unsigned short f32_to_bf16_rn(float f) {
  unsigned u = __float_as_uint(f);
  unsigned r = (u + 0x7FFFu + ((u >> 16) & 1u)) >> 16;
  return (unsigned short)r;
}
__device__ __forceinline__ float bf16_to_f32(unsigned short h) {
  return __uint_as_float(((unsigned)h) << 16);
}
__device__ __forceinline__ unsigned pack_bf16x2(float a, float b) {
  return (unsigned)f32_to_bf16_rn(a) | ((unsigned)f32_to_bf16_rn(b) << 16);
}
// colagg epilogue sO strides (f32 units)
constexpr int SOW = 17;
constexpr int SOC = 16 * SOW + 1;   // 273
constexpr size_t AROWT_OFF = 2097152;   // u16 offset within q/k region
// qkb plane offsets (u16, within batch q/k region)
constexpr size_t QH_OFF = 0;
constexpr size_t QL_OFF = 1048576;
constexpr size_t KH_OFF = 2097152;
constexpr size_t KL_OFF = 3145728;
// vtrans LDS strides (f32 units)
constexpr int VT_SC = 68;
constexpr int VT_SW = 16 * VT_SC + 4; // 1092
// vfrag per-batch stride (u16): 128w * 32cb * 4kt * 64lane * 8 = 8.4M
constexpr size_t VFRAG_B = (size_t)kW * 32 * 4 * 64 * 8;
}

// ---------------- pack W/bias into bf16 hi/lo planes [640][512] ----------------
__global__ __launch_bounds__(256) void pack_w(
    const float* __restrict__ Wq, const float* __restrict__ bq,
    const float* __restrict__ Wk, const float* __restrict__ bk,
    const float* __restrict__ Wv, const float* __restrict__ bv,
    short* __restrict__ wpk, float* __restrict__ ball) {
  const int r = blockIdx.x;      // 0..639
  const int t = threadIdx.x;     // 256
  const float* src;
  if (r < 64) {
    src = Wq + (size_t)r * kC;
    if (t == 0) ball[r] = bq[r];
  } else if (r < 128) {
    src = Wk + (size_t)(r - 64) * kC;
    if (t == 0) ball[r] = bk[r - 64];
  } else {
    src = Wv + (size_t)(r - 128) * kC;
    if (t == 0) ball[r] = bv[r - 128];
  }
#pragma unroll
  for (int p = 0; p < 2; ++p) {
    const int c = p * 256 + t;
    const float v = src[c];
    const unsigned short h = f32_to_bf16_rn(v);
    const unsigned short l = f32_to_bf16_rn(v - bf16_to_f32(h));
    wpk[(size_t)r * kC + c] = (short)h;
    wpk[(size_t)kO * kC + (size_t)r * kC + c] = (short)l;
  }
}

// ---------------- pack x (one batch): fp32 [c][l] -> bf16 hi/lo [l][c] ----------------
__global__ __launch_bounds__(256) void pack_x(
    const float* __restrict__ x, short* __restrict__ xpk, int b) {
  __shared__ float sT[64][65];
  const int l0 = blockIdx.x * 64;
  const int c0 = blockIdx.y * 64;
  const int t = threadIdx.x;
  const float* xb = x + (size_t)b * kC * kL;
#pragma unroll
  for (int p = 0; p < 4; ++p) {
    const int ch = p * 256 + t;
    const int c = ch >> 4, l4 = (ch & 15) * 4;
    float4 v = *(const float4*)(xb + (size_t)(c0 + c) * kL + l0 + l4);
    sT[c][l4 + 0] = v.x; sT[c][l4 + 1] = v.y; sT[c][l4 + 2] = v.z; sT[c][l4 + 3] = v.w;
  }
  __syncthreads();
#pragma unroll
  for (int p = 0; p < 2; ++p) {
    const int ch = p * 256 + t;
    const int l = ch >> 3, cg = ch & 7;
    short hi[8], lo[8];
#pragma unroll
    for (int j = 0; j < 8; ++j) {
      const float v = sT[cg * 8 + j][l];
      const unsigned short h = f32_to_bf16_rn(v);
      hi[j] = (short)h;
      lo[j] = (short)f32_to_bf16_rn(v - bf16_to_f32(h));
    }
    short* dh = xpk + (size_t)(l0 + l) * kC + c0 + cg * 8;
    *(bf16x8*)dh = *(bf16x8*)hi;
    *(bf16x8*)(dh + (size_t)kL * kC) = *(bf16x8*)lo;
  }
}

// ---------------- projection GEMM via bf16 MFMA, split precision ----------------
// Staging via global_load_lds (linear LDS dest, pre-swizzled global source).
// qk tile (mt==0) -> qkb bf16 hi/lo planes; v tiles -> vbf bf16 [c][l].
__global__ __launch_bounds__(256, 2) void proj_mfma(
    const short* __restrict__ xpk, const short* __restrict__ wpk,
    const float* __restrict__ ball, float* __restrict__ qkv, int b) {
  __shared__ short A_h[128 * 64];
  __shared__ short A_l[128 * 64];
  __shared__ short B_h[128 * 64];
  __shared__ short B_l[128 * 64];
  const int mt = blockIdx.x;          // 0..4
  const int n0 = blockIdx.y * 128;
  const int m0 = mt * 128;
  const bool qk = (mt == 0);
  const int t = threadIdx.x;
  const int wid = t >> 6, lane = t & 63;
  const int wr = wid >> 1, wc = wid & 1;
  const int lr = lane & 15, lg = lane >> 4;
  const int srow8 = lane >> 3;
  const int skg = (lane & 7) ^ srow8;

  f32x4 acc[4][4];
#pragma unroll
  for (int i = 0; i < 4; ++i)
#pragma unroll
    for (int j = 0; j < 4; ++j) acc[i][j] = (f32x4)(0.f);

  for (int kt = 0; kt < 8; ++kt) {
    const int k0 = kt * 64;
#pragma unroll
    for (int p = 0; p < 4; ++p) {
      const int ck = p * 4 + wid;
      const int row = ck * 8 + srow8;
      const short* srcA = wpk + (size_t)(m0 + row) * kC + k0 + skg * 8;
      const short* srcB = xpk + (size_t)(n0 + row) * kC + k0 + skg * 8;
      __builtin_amdgcn_global_load_lds(
          (const __attribute__((address_space(1))) void*)srcA,
          (__attribute__((address_space(3))) void*)&A_h[ck * 512], 16, 0, 0);
      __builtin_amdgcn_global_load_lds(
          (const __attribute__((address_space(1))) void*)(srcA + (size_t)kO * kC),
          (__attribute__((address_space(3))) void*)&A_l[ck * 512], 16, 0, 0);
      __builtin_amdgcn_global_load_lds(
          (const __attribute__((address_space(1))) void*)srcB,
          (__attribute__((address_space(3))) void*)&B_h[ck * 512], 16, 0, 0);
      if (qk)
        __builtin_amdgcn_global_load_lds(
            (const __attribute__((address_space(1))) void*)(srcB + (size_t)kL * kC),
            (__attribute__((address_space(3))) void*)&B_l[ck * 512], 16, 0, 0);
    }
    __syncthreads();
#pragma unroll
    for (int ks = 0; ks < 2; ++ks) {
      bf16x8 ah[4], al[4], bh[4], bl[4];
#pragma unroll
      for (int mf = 0; mf < 4; ++mf) {
        const int row = wr * 64 + mf * 16 + lr;
        const int kg = ks * 4 + lg;
        const int off = row * 64 + ((kg ^ (row & 7)) << 3);
        ah[mf] = *(const bf16x8*)&A_h[off];
        al[mf] = *(const bf16x8*)&A_l[off];
      }
#pragma unroll
      for (int nf = 0; nf < 4; ++nf) {
        const int row = wc * 64 + nf * 16 + lr;
        const int kg = ks * 4 + lg;
        const int off = row * 64 + ((kg ^ (row & 7)) << 3);
        bh[nf] = *(const bf16x8*)&B_h[off];
        if (qk) bl[nf] = *(const bf16x8*)&B_l[off];
      }
#pragma unroll
      for (int mf = 0; mf < 4; ++mf)
#pragma unroll
        for (int nf = 0; nf < 4; ++nf) {
          acc[mf][nf] = __builtin_amdgcn_mfma_f32_16x16x32_bf16(
              ah[mf], bh[nf], acc[mf][nf], 0, 0, 0);
          acc[mf][nf] = __builtin_amdgcn_mfma_f32_16x16x32_bf16(
              al[mf], bh[nf], acc[mf][nf], 0, 0, 0);
          if (qk)
            acc[mf][nf] = __builtin_amdgcn_mfma_f32_16x16x32_bf16(
                ah[mf], bl[nf], acc[mf][nf], 0, 0, 0);
        }
    }
    __syncthreads();
  }
  if (qk) {
    unsigned short* qw = (unsigned short*)qkv + (size_t)b * kO * kL * 2
        + (wr ? KH_OFF : QH_OFF);
#pragma unroll
    for (int mf = 0; mf < 4; ++mf) {
      const int c0 = mf * 16 + lg * 4;
#pragma unroll
      for (int nf = 0; nf < 4; ++nf) {
        const int l = n0 + wc * 64 + nf * 16 + lr;
        unsigned short hi4[4], lo4[4];
#pragma unroll
        for (int r = 0; r < 4; ++r) {
          const float val = acc[mf][nf][r] + ball[wr * 64 + c0 + r];
          const unsigned short h = f32_to_bf16_rn(val);
          hi4[r] = h;
          lo4[r] = f32_to_bf16_rn(val - bf16_to_f32(h));
        }
        unsigned short* d = qw + ((size_t)l * 64 + c0);
        *(uint2*)d = *(uint2*)hi4;
        *(uint2*)(d + QL_OFF) = *(uint2*)lo4;
      }
    }
  } else {
    // v tiles: write bf16 vbf[c][l] (front half of old fp32 v region)
    unsigned short* vbf =
        (unsigned short*)(qkv + ((size_t)b * kO + 128) * kL);
#pragma unroll
    for (int mf = 0; mf < 4; ++mf) {
#pragma unroll
      for (int r = 0; r < 4; ++r) {
        const int m = m0 + wr * 64 + mf * 16 + lg * 4 + r;
        const float bias = ball[m];
        unsigned short* dst = vbf + (size_t)(m - 128) * kL + n0 + wc * 64;
#pragma unroll
        for (int nf = 0; nf < 4; ++nf) {
          dst[nf * 16 + lr] = f32_to_bf16_rn(acc[mf][nf][r] + bias);
        }
      }
    }
  }
}

// ---------------- scores via MFMA, 3-pass split precision ----------------
template <int COL>
__global__ __launch_bounds__(256) void escore_mfma(
    const float* qkv, float* __restrict__ e) {
  const int bi = blockIdx.x;           // b*128 + idx
  const int b = bi >> 7, idx = bi & 127;
  const int t = threadIdx.x;
  const int wid = t >> 6, lane = t & 63;
  const int wj = wid >> 1, wh = wid & 1;
  const int lr = lane & 15, lg = lane >> 4;

  const unsigned short* qkb = (const unsigned short*)qkv + (size_t)b * kO * kL * 2;
  const size_t baseoff = COL ? (size_t)idx * 64 : (size_t)idx * 8192;
  const int rstride = COL ? 8192 : 64;

  f32x4 acc[4][4];
#pragma unroll
  for (int i = 0; i < 4; ++i)
#pragma unroll
    for (int j = 0; j < 4; ++j) acc[i][j] = (f32x4)(0.f);

#pragma unroll
  for (int ks = 0; ks < 2; ++ks) {
    bf16x8 ah[4], al[4], bh[4], bl[4];
#pragma unroll
    for (int mf = 0; mf < 4; ++mf) {
      const size_t ro = baseoff + (size_t)(wj * 64 + mf * 16 + lr) * rstride
          + ks * 32 + lg * 8;
      ah[mf] = *(const bf16x8*)(qkb + KH_OFF + ro);
      al[mf] = *(const bf16x8*)(qkb + KL_OFF + ro);
    }
#pragma unroll
    for (int nf = 0; nf < 4; ++nf) {
      const size_t ro = baseoff + (size_t)(wh * 64 + nf * 16 + lr) * rstride
          + ks * 32 + lg * 8;
      bh[nf] = *(const bf16x8*)(qkb + QH_OFF + ro);
      bl[nf] = *(const bf16x8*)(qkb + QL_OFF + ro);
    }
#pragma unroll
    for (int mf = 0; mf < 4; ++mf)
#pragma unroll
      for (int nf = 0; nf < 4; ++nf) {
        acc[mf][nf] = __builtin_amdgcn_mfma_f32_16x16x32_bf16(
            ah[mf], bh[nf], acc[mf][nf], 0, 0, 0);
        acc[mf][nf] = __builtin_amdgcn_mfma_f32_16x16x32_bf16(
            ah[mf], bl[nf], acc[mf][nf], 0, 0, 0);
        acc[mf][nf] = __builtin_amdgcn_mfma_f32_16x16x32_bf16(
            al[mf], bh[nf], acc[mf][nf], 0, 0, 0);
      }
  }
  const float NEG_INF = __int_as_float(0xff800000);
#pragma unroll
  for (int mf = 0; mf < 4; ++mf) {
    const int row0 = wj * 64 + mf * 16 + lg * 4;     // i or j
#pragma unroll
    for (int nf = 0; nf < 4; ++nf) {
      const int cl = wh * 64 + nf * 16 + lr;          // w or h
      float o[4];
#pragma unroll
      for (int r = 0; r < 4; ++r) {
        float v = acc[mf][nf][r];
        if (COL && (row0 + r == cl)) v = NEG_INF;
        o[r] = v;
      }
      float* dst;
      if (COL)
        dst = e + (((size_t)b * kH + cl) * kW + idx) * 256 + 128 + row0;
      else
        dst = e + (((size_t)b * kH + idx) * kW + cl) * 256 + row0;
      *(float4*)dst = *(const float4*)o;
    }
  }
}

// ---------------- softmax; row half -> bf16 arowT, col half -> bf16 afrag ----
__global__ __launch_bounds__(256) void softmax_kernel(
    float* __restrict__ e, float* qkv_base) {
  const int t = threadIdx.x;
  const int wv = t >> 6, lane = t & 63;
  const size_t pix = (size_t)blockIdx.x * 4 + wv;
  float* p = e + pix * 256 + lane * 4;
  float4 v = *(const float4*)p;
  float m = fmaxf(fmaxf(v.x, v.y), fmaxf(v.z, v.w));
#pragma unroll
  for (int off = 32; off > 0; off >>= 1) m = fmaxf(m, __shfl_xor(m, off, 64));
  float e0 = expf(v.x - m), e1 = expf(v.y - m), e2 = expf(v.z - m), e3 = expf(v.w - m);
  float s = e0 + e1 + e2 + e3;
#pragma unroll
  for (int off = 32; off > 0; off >>= 1) s += __shfl_xor(s, off, 64);
  const float inv = 1.0f / s;
  const float o0 = e0 * inv, o1 = e1 * inv, o2 = e2 * inv, o3 = e3 * inv;
  const int b = (int)(pix >> 14);
  const int h = (int)((pix >> 7) & 127);
  const int w = (int)(pix & 127);
  unsigned short* base = (unsigned short*)qkv_base + (size_t)b * kO * kL * 2;
  if (lane < 32) {
    unsigned short* dst = base + AROWT_OFF + (((size_t)h * kW + w) * 128 + lane * 4);
    *(uint2*)dst = make_uint2(pack_bf16x2(o0, o1), pack_bf16x2(o2, o3));
  } else {
    const int s32 = lane - 32;
    const int jb = s32 >> 3;
    const int lg = (s32 >> 1) & 3;
    const int eoff = (s32 & 1) * 4;
    const int hb = h >> 4, hr = h & 15;
    unsigned short* dst = base + (size_t)w * 16384
        + (((size_t)(jb * 8 + hb) * 64 + lg * 16 + hr) * 8 + eoff);
    *(uint2*)dst = make_uint2(pack_bf16x2(o0, o1), pack_bf16x2(o2, o3));
  }
}

// ---------------- vtrans: vbf bf16 [c][l] -> vfrag bf16 (MFMA A-frag order) ----
__global__ __launch_bounds__(256) void vtrans_kernel(
    const float* __restrict__ qkv, unsigned short* __restrict__ vfrag) {
  __shared__ float sT[16 * VT_SW];   // 69,888 B : [w16][c16][j64]
  const int cb = blockIdx.x;         // 0..31
  const int wt = blockIdx.y;         // 0..7
  const int b  = blockIdx.z;
  const int t = threadIdx.x;
  const int lane = t & 63, wd = t >> 6;
  const int lr = lane & 15, lg = lane >> 4;
  const unsigned short* vb =
      (const unsigned short*)(qkv + ((size_t)b * kO + 128) * kL)
      + (size_t)(cb * 16) * kL + wt * 16;
  unsigned short* vfb = vfrag + (size_t)b * VFRAG_B;

  for (int half = 0; half < 2; ++half) {
    const int j0 = half * 64;
#pragma unroll
    for (int p = 0; p < 16; ++p) {
      const int g = p * 256 + t;
      const int wq = g & 3;
      const int j = (g >> 2) & 63;
      const int ci = p;
      uint2 v2 = *(const uint2*)(vb + (size_t)ci * kL + (size_t)(j0 + j) * kW + wq * 4);
      float* d = sT + ci * VT_SC + j;
      d[(wq * 4 + 0) * VT_SW] = bf16_to_f32((unsigned short)(v2.x & 0xffff));
      d[(wq * 4 + 1) * VT_SW] = bf16_to_f32((unsigned short)(v2.x >> 16));
      d[(wq * 4 + 2) * VT_SW] = bf16_to_f32((unsigned short)(v2.y & 0xffff));
      d[(wq * 4 + 3) * VT_SW] = bf16_to_f32((unsigned short)(v2.y >> 16));
    }
    __syncthreads();
#pragma unroll
    for (int wi = 0; wi < 4; ++wi) {
      const int w = wd * 4 + wi;
#pragma unroll
      for (int ktl = 0; ktl < 2; ++ktl) {
        const float* s = sT + w * VT_SW + lr * VT_SC + ktl * 32 + lg * 8;
        float a[8];
        *(float4*)(a + 0) = *(const float4*)(s + 0);
        *(float4*)(a + 4) = *(const float4*)(s + 4);
        const int ktg = half * 2 + ktl;
        unsigned short* dst = vfb
            + ((((size_t)(wt * 16 + w) * 32 + cb) * 4 + ktg) * 64 + lane) * 8;
        uint4 o = make_uint4(pack_bf16x2(a[0], a[1]), pack_bf16x2(a[2], a[3]),
                             pack_bf16x2(a[4], a[5]), pack_bf16x2(a[6], a[7]));
        *(uint4*)dst = o;
      }
    }
    __syncthreads();
  }
}

// ---------------- col aggregation: direct frag loads, h64, pure STORE ----------------
__global__ __launch_bounds__(1024) void colagg_mfma(
    const float* qkv, const unsigned short* __restrict__ vfrag,
    float* __restrict__ out) {
  __shared__ float sO[64 * SOC];      // 69,888 B (epilogue only)
  const int gx = blockIdx.x;          // ct(8) + 8*ht(2)
  const int ct = gx & 7, ht = gx >> 3;
  const int c0 = ct * 64, h0 = ht * 64;
  const int w0 = blockIdx.y * 16;
  const int b = blockIdx.z;
  const int t = threadIdx.x;          // 0..1023
  const int wv = t >> 6, lane = t & 63;
  const int lr = lane & 15, lg = lane >> 4;
  const int w = w0 + wv;

  f32x4 acc[4][4];
#pragma unroll
  for (int i = 0; i < 4; ++i)
#pragma unroll
    for (int j = 0; j < 4; ++j) acc[i][j] = (f32x4)(0.f);

  const unsigned short* ab = (const unsigned short*)qkv + (size_t)b * kO * kL * 2
      + (size_t)w * 16384;
  const unsigned short* vfb = vfrag + (size_t)b * VFRAG_B
      + ((size_t)w * 32 + ct * 4) * 2048;

  for (int kt = 0; kt < 4; ++kt) {
    bf16x8 vf[4], af[4];
#pragma unroll
    for (int mf = 0; mf < 4; ++mf)
      vf[mf] = *(const bf16x8*)(vfb + ((size_t)mf * 2048 + kt * 512 + lane * 8));
#pragma unroll
    for (int nf = 0; nf < 4; ++nf)
      af[nf] = *(const bf16x8*)(
          ab + (((size_t)(kt * 8 + ht * 4 + nf) * 64 + lane) * 8));
#pragma unroll
    for (int mf = 0; mf < 4; ++mf)
#pragma unroll
      for (int nf = 0; nf < 4; ++nf)
        acc[mf][nf] = __builtin_amdgcn_mfma_f32_16x16x32_bf16(
            vf[mf], af[nf], acc[mf][nf], 0, 0, 0);
  }

  const int ew = t & 15, ehh = (t >> 4) & 15, ecb = t >> 8;
  for (int nf = 0; nf < 4; ++nf) {
    __syncthreads();
#pragma unroll
    for (int mf = 0; mf < 4; ++mf)
#pragma unroll
      for (int r = 0; r < 4; ++r)
        sO[(mf * 16 + lg * 4 + r) * SOC + lr * SOW + wv] = acc[mf][nf][r];
    __syncthreads();
#pragma unroll
    for (int q = 0; q < 16; ++q) {
      const int c = q * 4 + ecb;
      float* dst = out + (((size_t)b * kC + c0 + c) * kH + h0 + nf * 16 + ehh) * kW
          + w0 + ew;
      *dst = sO[c * SOC + ehh * SOW + ew];    // pure store (rowagg RMWs after)
    }
  }
}

// ---------------- row aggregation via bf16 MFMA (LDS-free, direct frags, RMW) ----
// out[b][c][h][w] += sum_i arowT[b][h][w][i] * vbf[c][h*128+i]
__global__ __launch_bounds__(256) void rowagg_mfma(
    const float* qkv, float* __restrict__ out) {
  const int ct = blockIdx.x;       // 0..3
  const int bh = blockIdx.y;
  const int b = bh >> 7, h = bh & 127;
  const int c0 = ct * 128;
  const int t = threadIdx.x;
  const int wid = t >> 6, lane = t & 63;
  const int wr = wid >> 1, wc = wid & 1;
  const int lr = lane & 15, lg = lane >> 4;

  f32x4 acc[4][4];
#pragma unroll
  for (int i = 0; i < 4; ++i)
#pragma unroll
    for (int j = 0; j < 4; ++j) acc[i][j] = (f32x4)(0.f);

  const unsigned short* vbf =
      (const unsigned short*)(qkv + ((size_t)b * kO + 128) * kL);
  const unsigned short* arbase = (const unsigned short*)qkv
      + (size_t)b * kO * kL * 2 + AROWT_OFF + (size_t)h * kW * 128;

#pragma unroll
  for (int s = 0; s < 4; ++s) {
    bf16x8 vfr[4], afr[4];
#pragma unroll
    for (int mf = 0; mf < 4; ++mf) {
      const int c = c0 + wr * 64 + mf * 16 + lr;
      vfr[mf] = *(const bf16x8*)(
          vbf + (size_t)c * kL + (size_t)h * kW + s * 32 + lg * 8);
    }
#pragma unroll
    for (int nf = 0; nf < 4; ++nf) {
      const int w = wc * 64 + nf * 16 + lr;
      afr[nf] = *(const bf16x8*)(arbase + (size_t)w * 128 + s * 32 + lg * 8);
    }
#pragma unroll
    for (int mf = 0; mf < 4; ++mf)
#pragma unroll
      for (int nf = 0; nf < 4; ++nf)
        acc[mf][nf] = __builtin_amdgcn_mfma_f32_16x16x32_bf16(
            vfr[mf], afr[nf], acc[mf][nf], 0, 0, 0);
  }
#pragma unroll
  for (int mf = 0; mf < 4; ++mf) {
#pragma unroll
    for (int r = 0; r < 4; ++r) {
      const int c = c0 + wr * 64 + mf * 16 + lg * 4 + r;
      float* dst = out + (((size_t)b * kC + c) * kH + h) * kW + wc * 64;
#pragma unroll
      for (int nf = 0; nf < 4; ++nf) {
        dst[nf * 16 + lr] += acc[mf][nf][r];
      }
    }
  }
}

extern "C" void kernel_launch(void* const* d_in, const int* in_sizes, int n_in,
                              void* d_out, int out_size, void* d_ws, size_t ws_size,
                              hipStream_t stream) {
  (void)in_sizes; (void)n_in; (void)out_size; (void)ws_size;
  const float* x  = (const float*)d_in[0];
  const float* Wq = (const float*)d_in[1];
  const float* bq = (const float*)d_in[2];
  const float* Wk = (const float*)d_in[3];
  const float* bk = (const float*)d_in[4];
  const float* Wv = (const float*)d_in[5];
  const float* bv = (const float*)d_in[6];
  float* out = (float*)d_out;
  float* ws  = (float*)d_ws;

  short* wpk = (short*)(ws + OFF_WALL);
  float* ball = ws + OFF_BALL;
  float* qkv  = ws + OFF_QKV;
  float* e    = ws + OFF_E;
  short* xpk  = (short*)(ws + OFF_E);
  unsigned short* vfrag = (unsigned short*)(ws + OFF_E);

  pack_w<<<dim3(kO), dim3(256), 0, stream>>>(Wq, bq, Wk, bk, Wv, bv, wpk, ball);
  for (int b = 0; b < kB; ++b) {
    pack_x<<<dim3(kL / 64, kC / 64), dim3(256), 0, stream>>>(x, xpk, b);
    proj_mfma<<<dim3(5, kL / 128), dim3(256), 0, stream>>>(xpk, wpk, ball, qkv, b);
  }
  escore_mfma<0><<<dim3(kB * kH), dim3(256), 0, stream>>>(qkv, e);
  escore_mfma<1><<<dim3(kB * kW), dim3(256), 0, stream>>>(qkv, e);
  softmax_kernel<<<dim3(kB * kH * kW / 4), dim3(256), 0, stream>>>(e, qkv);
  vtrans_kernel<<<dim3(32, 8, kB), dim3(256), 0, stream>>>(qkv, vfrag);
  colagg_mfma<<<dim3(16, kW / 16, kB), dim3(1024), 0, stream>>>(qkv, vfrag, out);
  rowagg_mfma<<<dim3(4, kB * kH), dim3(256), 0, stream>>>(qkv, out);
}

// Round 12
// 464.277 us; speedup vs baseline: 1.0651x; 1.0651x over previous
//
#include <hip/hip_runtime.h>
#include <hip/hip_bf16.h>

namespace {
constexpr int kB = 4;
constexpr int kC = 512;
constexpr int kH = 128;
constexpr int kW = 128;
constexpr int kCQK = 64;
constexpr int kL = kH * kW;   // 16384
constexpr int kO = 640;       // rows: [0,64)=Wq, [64,128)=Wk, [128,640)=Wv

// workspace layout (float offsets)
constexpr size_t OFF_WALL = 0;                          // wpk: 640*512*2 bf16
constexpr size_t OFF_BALL = (size_t)kO * kC;            // 640
constexpr size_t OFF_QKV  = OFF_BALL + kO;              // B*640*L region
constexpr size_t OFF_E    = OFF_QKV + (size_t)kB * kO * kL;  // B*H*W*256 fp32
constexpr size_t WS_FLOATS = OFF_E + (size_t)kB * kH * kW * 256;
// Per-batch q/k region (first 128 fp32-rows = 8.4MB/b):
//   proj writes qkb bf16 planes: qh@0, ql@1M, kh@2M, kl@3M (u16 offsets)
//   escore reads qkb; softmax overwrites with afrag[0,2M) + arowT[2M,4M)
// Per-batch v region (rows 128..640, 33.5MB/b), as u16:
//   [0 .. 8.4M)     vbf[c 512][l 16384] bf16   (proj)
//   [8.4M .. 16.8M) ctmp[c 512][h 128][w 128] bf16  (colagg partial -> rowagg)
// e region (67MB): xpk (pre-proj) -> scores fp32 -> vfrag bf16

typedef __attribute__((ext_vector_type(8))) short bf16x8;
typedef __attribute__((ext_vector_type(4))) float f32x4;

__device__ __forceinline__ unsigned short f32_to_bf16_rn(float f) {
  unsigned u = __float_as_uint(f);
  unsigned r = (u + 0x7FFFu + ((u >> 16) & 1u)) >> 16;
  return (unsigned short)r;
}
__device__ __forceinline__ float bf16_to_f32(unsigned short h) {
  return __uint_as_float(((unsigned)h) << 16);
}
__device__ __forceinline__ unsigned pack_bf16x2(float a, float b) {
  return (unsigned)f32_to_bf16_rn(a) | ((unsigned)f32_to_bf16_rn(b) << 16);
}
// colagg epilogue sO strides (f32 units)
constexpr int SOW = 17;
constexpr int SOC = 16 * SOW + 1;   // 273
constexpr size_t AROWT_OFF = 2097152;   // u16 offset within q/k region
// qkb plane offsets (u16, within batch q/k region)
constexpr size_t QH_OFF = 0;
constexpr size_t QL_OFF = 1048576;
constexpr size_t KH_OFF = 2097152;
constexpr size_t KL_OFF = 3145728;
// v-region u16 offsets
constexpr size_t CTMP_OFF = 8388608;    // u16 offset of ctmp within v region
// vtrans LDS strides (f32 units)
constexpr int VT_SC = 68;
constexpr int VT_SW = 16 * VT_SC + 4; // 1092
// vfrag per-batch stride (u16)
constexpr size_t VFRAG_B = (size_t)kW * 32 * 4 * 64 * 8;
}

// ---------------- pack W/bias into bf16 hi/lo planes [640][512] ----------------
__global__ __launch_bounds__(256) void pack_w(
    const float* __restrict__ Wq, const float* __restrict__ bq,
    const float* __restrict__ Wk, const float* __restrict__ bk,
    const float* __restrict__ Wv, const float* __restrict__ bv,
    short* __restrict__ wpk, float* __restrict__ ball) {
  const int r = blockIdx.x;      // 0..639
  const int t = threadIdx.x;     // 256
  const float* src;
  if (r < 64) {
    src = Wq + (size_t)r * kC;
    if (t == 0) ball[r] = bq[r];
  } else if (r < 128) {
    src = Wk + (size_t)(r - 64) * kC;
    if (t == 0) ball[r] = bk[r - 64];
  } else {
    src = Wv + (size_t)(r - 128) * kC;
    if (t == 0) ball[r] = bv[r - 128];
  }
#pragma unroll
  for (int p = 0; p < 2; ++p) {
    const int c = p * 256 + t;
    const float v = src[c];
    const unsigned short h = f32_to_bf16_rn(v);
    const unsigned short l = f32_to_bf16_rn(v - bf16_to_f32(h));
    wpk[(size_t)r * kC + c] = (short)h;
    wpk[(size_t)kO * kC + (size_t)r * kC + c] = (short)l;
  }
}

// ---------------- pack x (one batch): fp32 [c][l] -> bf16 hi/lo [l][c] ----------------
__global__ __launch_bounds__(256) void pack_x(
    const float* __restrict__ x, short* __restrict__ xpk, int b) {
  __shared__ float sT[64][65];
  const int l0 = blockIdx.x * 64;
  const int c0 = blockIdx.y * 64;
  const int t = threadIdx.x;
  const float* xb = x + (size_t)b * kC * kL;
#pragma unroll
  for (int p = 0; p < 4; ++p) {
    const int ch = p * 256 + t;
    const int c = ch >> 4, l4 = (ch & 15) * 4;
    float4 v = *(const float4*)(xb + (size_t)(c0 + c) * kL + l0 + l4);
    sT[c][l4 + 0] = v.x; sT[c][l4 + 1] = v.y; sT[c][l4 + 2] = v.z; sT[c][l4 + 3] = v.w;
  }
  __syncthreads();
#pragma unroll
  for (int p = 0; p < 2; ++p) {
    const int ch = p * 256 + t;
    const int l = ch >> 3, cg = ch & 7;
    short hi[8], lo[8];
#pragma unroll
    for (int j = 0; j < 8; ++j) {
      const float v = sT[cg * 8 + j][l];
      const unsigned short h = f32_to_bf16_rn(v);
      hi[j] = (short)h;
      lo[j] = (short)f32_to_bf16_rn(v - bf16_to_f32(h));
    }
    short* dh = xpk + (size_t)(l0 + l) * kC + c0 + cg * 8;
    *(bf16x8*)dh = *(bf16x8*)hi;
    *(bf16x8*)(dh + (size_t)kL * kC) = *(bf16x8*)lo;
  }
}

// ---------------- projection GEMM via bf16 MFMA, split precision ----------------
__global__ __launch_bounds__(256, 2) void proj_mfma(
    const short* __restrict__ xpk, const short* __restrict__ wpk,
    const float* __restrict__ ball, float* __restrict__ qkv, int b) {
  __shared__ short A_h[128 * 64];
  __shared__ short A_l[128 * 64];
  __shared__ short B_h[128 * 64];
  __shared__ short B_l[128 * 64];
  const int mt = blockIdx.x;          // 0..4
  const int n0 = blockIdx.y * 128;
  const int m0 = mt * 128;
  const bool qk = (mt == 0);
  const int t = threadIdx.x;
  const int wid = t >> 6, lane = t & 63;
  const int wr = wid >> 1, wc = wid & 1;
  const int lr = lane & 15, lg = lane >> 4;
  const int srow8 = lane >> 3;
  const int skg = (lane & 7) ^ srow8;

  f32x4 acc[4][4];
#pragma unroll
  for (int i = 0; i < 4; ++i)
#pragma unroll
    for (int j = 0; j < 4; ++j) acc[i][j] = (f32x4)(0.f);

  for (int kt = 0; kt < 8; ++kt) {
    const int k0 = kt * 64;
#pragma unroll
    for (int p = 0; p < 4; ++p) {
      const int ck = p * 4 + wid;
      const int row = ck * 8 + srow8;
      const short* srcA = wpk + (size_t)(m0 + row) * kC + k0 + skg * 8;
      const short* srcB = xpk + (size_t)(n0 + row) * kC + k0 + skg * 8;
      __builtin_amdgcn_global_load_lds(
          (const __attribute__((address_space(1))) void*)srcA,
          (__attribute__((address_space(3))) void*)&A_h[ck * 512], 16, 0, 0);
      __builtin_amdgcn_global_load_lds(
          (const __attribute__((address_space(1))) void*)(srcA + (size_t)kO * kC),
          (__attribute__((address_space(3))) void*)&A_l[ck * 512], 16, 0, 0);
      __builtin_amdgcn_global_load_lds(
          (const __attribute__((address_space(1))) void*)srcB,
          (__attribute__((address_space(3))) void*)&B_h[ck * 512], 16, 0, 0);
      if (qk)
        __builtin_amdgcn_global_load_lds(
            (const __attribute__((address_space(1))) void*)(srcB + (size_t)kL * kC),
            (__attribute__((address_space(3))) void*)&B_l[ck * 512], 16, 0, 0);
    }
    __syncthreads();
#pragma unroll
    for (int ks = 0; ks < 2; ++ks) {
      bf16x8 ah[4], al[4], bh[4], bl[4];
#pragma unroll
      for (int mf = 0; mf < 4; ++mf) {
        const int row = wr * 64 + mf * 16 + lr;
        const int kg = ks * 4 + lg;
        const int off = row * 64 + ((kg ^ (row & 7)) << 3);
        ah[mf] = *(const bf16x8*)&A_h[off];
        al[mf] = *(const bf16x8*)&A_l[off];
      }
#pragma unroll
      for (int nf = 0; nf < 4; ++nf) {
        const int row = wc * 64 + nf * 16 + lr;
        const int kg = ks * 4 + lg;
        const int off = row * 64 + ((kg ^ (row & 7)) << 3);
        bh[nf] = *(const bf16x8*)&B_h[off];
        if (qk) bl[nf] = *(const bf16x8*)&B_l[off];
      }
#pragma unroll
      for (int mf = 0; mf < 4; ++mf)
#pragma unroll
        for (int nf = 0; nf < 4; ++nf) {
          acc[mf][nf] = __builtin_amdgcn_mfma_f32_16x16x32_bf16(
              ah[mf], bh[nf], acc[mf][nf], 0, 0, 0);
          acc[mf][nf] = __builtin_amdgcn_mfma_f32_16x16x32_bf16(
              al[mf], bh[nf], acc[mf][nf], 0, 0, 0);
          if (qk)
            acc[mf][nf] = __builtin_amdgcn_mfma_f32_16x16x32_bf16(
                ah[mf], bl[nf], acc[mf][nf], 0, 0, 0);
        }
    }
    __syncthreads();
  }
  if (qk) {
    unsigned short* qw = (unsigned short*)qkv + (size_t)b * kO * kL * 2
        + (wr ? KH_OFF : QH_OFF);
#pragma unroll
    for (int mf = 0; mf < 4; ++mf) {
      const int c0 = mf * 16 + lg * 4;
#pragma unroll
      for (int nf = 0; nf < 4; ++nf) {
        const int l = n0 + wc * 64 + nf * 16 + lr;
        unsigned short hi4[4], lo4[4];
#pragma unroll
        for (int r = 0; r < 4; ++r) {
          const float val = acc[mf][nf][r] + ball[wr * 64 + c0 + r];
          const unsigned short h = f32_to_bf16_rn(val);
          hi4[r] = h;
          lo4[r] = f32_to_bf16_rn(val - bf16_to_f32(h));
        }
        unsigned short* d = qw + ((size_t)l * 64 + c0);
        *(uint2*)d = *(uint2*)hi4;
        *(uint2*)(d + QL_OFF) = *(uint2*)lo4;
      }
    }
  } else {
    unsigned short* vbf =
        (unsigned short*)(qkv + ((size_t)b * kO + 128) * kL);
#pragma unroll
    for (int mf = 0; mf < 4; ++mf) {
#pragma unroll
      for (int r = 0; r < 4; ++r) {
        const int m = m0 + wr * 64 + mf * 16 + lg * 4 + r;
        const float bias = ball[m];
        unsigned short* dst = vbf + (size_t)(m - 128) * kL + n0 + wc * 64;
#pragma unroll
        for (int nf = 0; nf < 4; ++nf) {
          dst[nf * 16 + lr] = f32_to_bf16_rn(acc[mf][nf][r] + bias);
        }
      }
    }
  }
}

// ---------------- scores via MFMA, 3-pass split precision ----------------
template <int COL>
__global__ __launch_bounds__(256) void escore_mfma(
    const float* qkv, float* __restrict__ e) {
  const int bi = blockIdx.x;           // b*128 + idx
  const int b = bi >> 7, idx = bi & 127;
  const int t = threadIdx.x;
  const int wid = t >> 6, lane = t & 63;
  const int wj = wid >> 1, wh = wid & 1;
  const int lr = lane & 15, lg = lane >> 4;

  const unsigned short* qkb = (const unsigned short*)qkv + (size_t)b * kO * kL * 2;
  const size_t baseoff = COL ? (size_t)idx * 64 : (size_t)idx * 8192;
  const int rstride = COL ? 8192 : 64;

  f32x4 acc[4][4];
#pragma unroll
  for (int i = 0; i < 4; ++i)
#pragma unroll
    for (int j = 0; j < 4; ++j) acc[i][j] = (f32x4)(0.f);

#pragma unroll
  for (int ks = 0; ks < 2; ++ks) {
    bf16x8 ah[4], al[4], bh[4], bl[4];
#pragma unroll
    for (int mf = 0; mf < 4; ++mf) {
      const size_t ro = baseoff + (size_t)(wj * 64 + mf * 16 + lr) * rstride
          + ks * 32 + lg * 8;
      ah[mf] = *(const bf16x8*)(qkb + KH_OFF + ro);
      al[mf] = *(const bf16x8*)(qkb + KL_OFF + ro);
    }
#pragma unroll
    for (int nf = 0; nf < 4; ++nf) {
      const size_t ro = baseoff + (size_t)(wh * 64 + nf * 16 + lr) * rstride
          + ks * 32 + lg * 8;
      bh[nf] = *(const bf16x8*)(qkb + QH_OFF + ro);
      bl[nf] = *(const bf16x8*)(qkb + QL_OFF + ro);
    }
#pragma unroll
    for (int mf = 0; mf < 4; ++mf)
#pragma unroll
      for (int nf = 0; nf < 4; ++nf) {
        acc[mf][nf] = __builtin_amdgcn_mfma_f32_16x16x32_bf16(
            ah[mf], bh[nf], acc[mf][nf], 0, 0, 0);
        acc[mf][nf] = __builtin_amdgcn_mfma_f32_16x16x32_bf16(
            ah[mf], bl[nf], acc[mf][nf], 0, 0, 0);
        acc[mf][nf] = __builtin_amdgcn_mfma_f32_16x16x32_bf16(
            al[mf], bh[nf], acc[mf][nf], 0, 0, 0);
      }
  }
  const float NEG_INF = __int_as_float(0xff800000);
#pragma unroll
  for (int mf = 0; mf < 4; ++mf) {
    const int row0 = wj * 64 + mf * 16 + lg * 4;     // i or j
#pragma unroll
    for (int nf = 0; nf < 4; ++nf) {
      const int cl = wh * 64 + nf * 16 + lr;          // w or h
      float o[4];
#pragma unroll
      for (int r = 0; r < 4; ++r) {
        float v = acc[mf][nf][r];
        if (COL && (row0 + r == cl)) v = NEG_INF;
        o[r] = v;
      }
      float* dst;
      if (COL)
        dst = e + (((size_t)b * kH + cl) * kW + idx) * 256 + 128 + row0;
      else
        dst = e + (((size_t)b * kH + idx) * kW + cl) * 256 + row0;
      *(float4*)dst = *(const float4*)o;
    }
  }
}

// ---------------- softmax; row half -> bf16 arowT, col half -> bf16 afrag ----
__global__ __launch_bounds__(256) void softmax_kernel(
    float* __restrict__ e, float* qkv_base) {
  const int t = threadIdx.x;
  const int wv = t >> 6, lane = t & 63;
  const size_t pix = (size_t)blockIdx.x * 4 + wv;
  float* p = e + pix * 256 + lane * 4;
  float4 v = *(const float4*)p;
  float m = fmaxf(fmaxf(v.x, v.y), fmaxf(v.z, v.w));
#pragma unroll
  for (int off = 32; off > 0; off >>= 1) m = fmaxf(m, __shfl_xor(m, off, 64));
  float e0 = expf(v.x - m), e1 = expf(v.y - m), e2 = expf(v.z - m), e3 = expf(v.w - m);
  float s = e0 + e1 + e2 + e3;
#pragma unroll
  for (int off = 32; off > 0; off >>= 1) s += __shfl_xor(s, off, 64);
  const float inv = 1.0f / s;
  const float o0 = e0 * inv, o1 = e1 * inv, o2 = e2 * inv, o3 = e3 * inv;
  const int b = (int)(pix >> 14);
  const int h = (int)((pix >> 7) & 127);
  const int w = (int)(pix & 127);
  unsigned short* base = (unsigned short*)qkv_base + (size_t)b * kO * kL * 2;
  if (lane < 32) {
    unsigned short* dst = base + AROWT_OFF + (((size_t)h * kW + w) * 128 + lane * 4);
    *(uint2*)dst = make_uint2(pack_bf16x2(o0, o1), pack_bf16x2(o2, o3));
  } else {
    const int s32 = lane - 32;
    const int jb = s32 >> 3;
    const int lg = (s32 >> 1) & 3;
    const int eoff = (s32 & 1) * 4;
    const int hb = h >> 4, hr = h & 15;
    unsigned short* dst = base + (size_t)w * 16384
        + (((size_t)(jb * 8 + hb) * 64 + lg * 16 + hr) * 8 + eoff);
    *(uint2*)dst = make_uint2(pack_bf16x2(o0, o1), pack_bf16x2(o2, o3));
  }
}

// ---------------- vtrans: vbf bf16 [c][l] -> vfrag bf16 (MFMA A-frag order) ----
__global__ __launch_bounds__(256) void vtrans_kernel(
    const float* __restrict__ qkv, unsigned short* __restrict__ vfrag) {
  __shared__ float sT[16 * VT_SW];   // 69,888 B : [w16][c16][j64]
  const int cb = blockIdx.x;         // 0..31
  const int wt = blockIdx.y;         // 0..7
  const int b  = blockIdx.z;
  const int t = threadIdx.x;
  const int lane = t & 63, wd = t >> 6;
  const int lr = lane & 15, lg = lane >> 4;
  const unsigned short* vb =
      (const unsigned short*)(qkv + ((size_t)b * kO + 128) * kL)
      + (size_t)(cb * 16) * kL + wt * 16;
  unsigned short* vfb = vfrag + (size_t)b * VFRAG_B;

  for (int half = 0; half < 2; ++half) {
    const int j0 = half * 64;
#pragma unroll
    for (int p = 0; p < 16; ++p) {
      const int g = p * 256 + t;
      const int wq = g & 3;
      const int j = (g >> 2) & 63;
      const int ci = p;
      uint2 v2 = *(const uint2*)(vb + (size_t)ci * kL + (size_t)(j0 + j) * kW + wq * 4);
      float* d = sT + ci * VT_SC + j;
      d[(wq * 4 + 0) * VT_SW] = bf16_to_f32((unsigned short)(v2.x & 0xffff));
      d[(wq * 4 + 1) * VT_SW] = bf16_to_f32((unsigned short)(v2.x >> 16));
      d[(wq * 4 + 2) * VT_SW] = bf16_to_f32((unsigned short)(v2.y & 0xffff));
      d[(wq * 4 + 3) * VT_SW] = bf16_to_f32((unsigned short)(v2.y >> 16));
    }
    __syncthreads();
#pragma unroll
    for (int wi = 0; wi < 4; ++wi) {
      const int w = wd * 4 + wi;
#pragma unroll
      for (int ktl = 0; ktl < 2; ++ktl) {
        const float* s = sT + w * VT_SW + lr * VT_SC + ktl * 32 + lg * 8;
        float a[8];
        *(float4*)(a + 0) = *(const float4*)(s + 0);
        *(float4*)(a + 4) = *(const float4*)(s + 4);
        const int ktg = half * 2 + ktl;
        unsigned short* dst = vfb
            + ((((size_t)(wt * 16 + w) * 32 + cb) * 4 + ktg) * 64 + lane) * 8;
        uint4 o = make_uint4(pack_bf16x2(a[0], a[1]), pack_bf16x2(a[2], a[3]),
                             pack_bf16x2(a[4], a[5]), pack_bf16x2(a[6], a[7]));
        *(uint4*)dst = o;
      }
    }
    __syncthreads();
  }
}

// ---------------- col aggregation: direct frag loads; writes bf16 ctmp ----------------
__global__ __launch_bounds__(1024) void colagg_mfma(
    float* qkv, const unsigned short* __restrict__ vfrag) {
  __shared__ float sO[64 * SOC];      // epilogue only
  const int gx = blockIdx.x;          // ct(8) + 8*ht(2)
  const int ct = gx & 7, ht = gx >> 3;
  const int c0 = ct * 64, h0 = ht * 64;
  const int w0 = blockIdx.y * 16;
  const int b = blockIdx.z;
  const int t = threadIdx.x;          // 0..1023
  const int wv = t >> 6, lane = t & 63;
  const int lr = lane & 15, lg = lane >> 4;
  const int w = w0 + wv;

  f32x4 acc[4][4];
#pragma unroll
  for (int i = 0; i < 4; ++i)
#pragma unroll
    for (int j = 0; j < 4; ++j) acc[i][j] = (f32x4)(0.f);

  const unsigned short* ab = (const unsigned short*)qkv + (size_t)b * kO * kL * 2
      + (size_t)w * 16384;
  const unsigned short* vfb = vfrag + (size_t)b * VFRAG_B
      + ((size_t)w * 32 + ct * 4) * 2048;
  unsigned short* ctmp =
      (unsigned short*)(qkv + ((size_t)b * kO + 128) * kL) + CTMP_OFF;

  for (int kt = 0; kt < 4; ++kt) {
    bf16x8 vf[4], af[4];
#pragma unroll
    for (int mf = 0; mf < 4; ++mf)
      vf[mf] = *(const bf16x8*)(vfb + ((size_t)mf * 2048 + kt * 512 + lane * 8));
#pragma unroll
    for (int nf = 0; nf < 4; ++nf)
      af[nf] = *(const bf16x8*)(
          ab + (((size_t)(kt * 8 + ht * 4 + nf) * 64 + lane) * 8));
#pragma unroll
    for (int mf = 0; mf < 4; ++mf)
#pragma unroll
      for (int nf = 0; nf < 4; ++nf)
        acc[mf][nf] = __builtin_amdgcn_mfma_f32_16x16x32_bf16(
            vf[mf], af[nf], acc[mf][nf], 0, 0, 0);
  }

  const int ew = t & 15, ehh = (t >> 4) & 15, ecb = t >> 8;
  for (int nf = 0; nf < 4; ++nf) {
    __syncthreads();
#pragma unroll
    for (int mf = 0; mf < 4; ++mf)
#pragma unroll
      for (int r = 0; r < 4; ++r)
        sO[(mf * 16 + lg * 4 + r) * SOC + lr * SOW + wv] = acc[mf][nf][r];
    __syncthreads();
#pragma unroll
    for (int q = 0; q < 16; ++q) {
      const int c = q * 4 + ecb;
      unsigned short* dst = ctmp + ((size_t)(c0 + c) * kL
          + (size_t)(h0 + nf * 16 + ehh) * kW + w0 + ew);
      *dst = f32_to_bf16_rn(sO[c * SOC + ehh * SOW + ew]);
    }
  }
}

// ---------------- row aggregation: direct frags + ctmp add, pure store ----------------
// out[b][c][h][w] = ctmp[c][h][w] + sum_i arowT[b][h][w][i] * vbf[c][h*128+i]
__global__ __launch_bounds__(256) void rowagg_mfma(
    const float* qkv, float* __restrict__ out) {
  const int ct = blockIdx.x;       // 0..3
  const int bh = blockIdx.y;
  const int b = bh >> 7, h = bh & 127;
  const int c0 = ct * 128;
  const int t = threadIdx.x;
  const int wid = t >> 6, lane = t & 63;
  const int wr = wid >> 1, wc = wid & 1;
  const int lr = lane & 15, lg = lane >> 4;

  f32x4 acc[4][4];
#pragma unroll
  for (int i = 0; i < 4; ++i)
#pragma unroll
    for (int j = 0; j < 4; ++j) acc[i][j] = (f32x4)(0.f);

  const unsigned short* vbf =
      (const unsigned short*)(qkv + ((size_t)b * kO + 128) * kL);
  const unsigned short* ctmp = vbf + CTMP_OFF;
  const unsigned short* arbase = (const unsigned short*)qkv
      + (size_t)b * kO * kL * 2 + AROWT_OFF + (size_t)h * kW * 128;

#pragma unroll
  for (int s = 0; s < 4; ++s) {
    bf16x8 vfr[4], afr[4];
#pragma unroll
    for (int mf = 0; mf < 4; ++mf) {
      const int c = c0 + wr * 64 + mf * 16 + lr;
      vfr[mf] = *(const bf16x8*)(
          vbf + (size_t)c * kL + (size_t)h * kW + s * 32 + lg * 8);
    }
#pragma unroll
    for (int nf = 0; nf < 4; ++nf) {
      const int w = wc * 64 + nf * 16 + lr;
      afr[nf] = *(const bf16x8*)(arbase + (size_t)w * 128 + s * 32 + lg * 8);
    }
#pragma unroll
    for (int mf = 0; mf < 4; ++mf)
#pragma unroll
      for (int nf = 0; nf < 4; ++nf)
        acc[mf][nf] = __builtin_amdgcn_mfma_f32_16x16x32_bf16(
            vfr[mf], afr[nf], acc[mf][nf], 0, 0, 0);
  }
#pragma unroll
  for (int mf = 0; mf < 4; ++mf) {
#pragma unroll
    for (int r = 0; r < 4; ++r) {
      const int c = c0 + wr * 64 + mf * 16 + lg * 4 + r;
      const unsigned short* csrc = ctmp + (size_t)c * kL + (size_t)h * kW + wc * 64;
      float* dst = out + (((size_t)b * kC + c) * kH + h) * kW + wc * 64;
#pragma unroll
      for (int nf = 0; nf < 4; ++nf) {
        dst[nf * 16 + lr] =
            acc[mf][nf][r] + bf16_to_f32(csrc[nf * 16 + lr]);
      }
    }
  }
}

extern "C" void kernel_launch(void* const* d_in, const int* in_sizes, int n_in,
                              void* d_out, int out_size, void* d_ws, size_t ws_size,
                              hipStream_t stream) {
  (void)in_sizes; (void)n_in; (void)out_size; (void)ws_size;
  const float* x  = (const float*)d_in[0];
  const float* Wq = (const float*)d_in[1];
  const float* bq = (const float*)d_in[2];
  const float* Wk = (const float*)d_in[3];
  const float* bk = (const float*)d_in[4];
  const float* Wv = (const float*)d_in[5];
  const float* bv = (const float*)d_in[6];
  float* out = (float*)d_out;
  float* ws  = (float*)d_ws;

  short* wpk = (short*)(ws + OFF_WALL);
  float* ball = ws + OFF_BALL;
  float* qkv  = ws + OFF_QKV;
  float* e    = ws + OFF_E;
  short* xpk  = (short*)(ws + OFF_E);
  unsigned short* vfrag = (unsigned short*)(ws + OFF_E);

  pack_w<<<dim3(kO), dim3(256), 0, stream>>>(Wq, bq, Wk, bk, Wv, bv, wpk, ball);
  for (int b = 0; b < kB; ++b) {
    pack_x<<<dim3(kL / 64, kC / 64), dim3(256), 0, stream>>>(x, xpk, b);
    proj_mfma<<<dim3(5, kL / 128), dim3(256), 0, stream>>>(xpk, wpk, ball, qkv, b);
  }
  escore_mfma<0><<<dim3(kB * kH), dim3(256), 0, stream>>>(qkv, e);
  escore_mfma<1><<<dim3(kB * kW), dim3(256), 0, stream>>>(qkv, e);
  softmax_kernel<<<dim3(kB * kH * kW / 4), dim3(256), 0, stream>>>(e, qkv);
  vtrans_kernel<<<dim3(32, 8, kB), dim3(256), 0, stream>>>(qkv, vfrag);
  colagg_mfma<<<dim3(16, kW / 16, kB), dim3(1024), 0, stream>>>(qkv, vfrag);
  rowagg_mfma<<<dim3(4, kB * kH), dim3(256), 0, stream>>>(qkv, out);
}

// Round 13
// 415.913 us; speedup vs baseline: 1.1889x; 1.1163x over previous
//
#include <hip/hip_runtime.h>
#include <hip/hip_bf16.h>

namespace {
constexpr int kB = 4;
constexpr int kC = 512;
constexpr int kH = 128;
constexpr int kW = 128;
constexpr int kCQK = 64;
constexpr int kL = kH * kW;   // 16384
constexpr int kO = 640;       // rows: [0,64)=Wq, [64,128)=Wk, [128,640)=Wv

// workspace layout (float offsets)
constexpr size_t OFF_WALL = 0;                          // wpk: 640*512*2 bf16
constexpr size_t OFF_BALL = (size_t)kO * kC;            // 640
constexpr size_t OFF_QKV  = OFF_BALL + kO;              // B*640*L region
constexpr size_t OFF_E    = OFF_QKV + (size_t)kB * kO * kL;  // B*H*W*256 fp32
constexpr size_t WS_FLOATS = OFF_E + (size_t)kB * kH * kW * 256;
// Per-batch q/k region (first 128 fp32-rows = 8.4MB/b):
//   proj writes qkb bf16 planes: qh@0, ql@1M, kh@2M, kl@3M (u16 offsets)
//   escore reads qkb; softmax overwrites with afrag[0,2M) + arowT[2M,4M)
// Per-batch v region (rows 128..640, 33.5MB/b), as u16:
//   [0 .. 8.4M)     vbf[c 512][l 16384] bf16   (proj)
//   [8.4M .. 16.8M) ctmp[c 512][h 128][w 128] bf16  (colagg partial -> rowagg)
// e region (67MB): xpk (pre-proj) -> scores fp32 -> vfrag bf16

typedef __attribute__((ext_vector_type(8))) short bf16x8;
typedef __attribute__((ext_vector_type(4))) float f32x4;

__device__ __forceinline__ unsigned short f32_to_bf16_rn(float f) {
  unsigned u = __float_as_uint(f);
  unsigned r = (u + 0x7FFFu + ((u >> 16) & 1u)) >> 16;
  return (unsigned short)r;
}
__device__ __forceinline__ float bf16_to_f32(unsigned short h) {
  return __uint_as_float(((unsigned)h) << 16);
}
__device__ __forceinline__ unsigned pack_bf16x2(float a, float b) {
  return (unsigned)f32_to_bf16_rn(a) | ((unsigned)f32_to_bf16_rn(b) << 16);
}
// colagg epilogue sO strides (f32 units): [c 64][h 16][w 16]
constexpr int SOW = 17;
constexpr int SOC = 16 * SOW + 1;   // 273
// rowagg epilogue sO strides (f32 units): [c 64][w 128(+4)]
constexpr int ROW_SW = 132;
constexpr size_t AROWT_OFF = 2097152;   // u16 offset within q/k region
// qkb plane offsets (u16, within batch q/k region)
constexpr size_t QH_OFF = 0;
constexpr size_t QL_OFF = 1048576;
constexpr size_t KH_OFF = 2097152;
constexpr size_t KL_OFF = 3145728;
// v-region u16 offsets
constexpr size_t CTMP_OFF = 8388608;    // u16 offset of ctmp within v region
// vtrans LDS strides (f32 units)
constexpr int VT_SC = 68;
constexpr int VT_SW = 16 * VT_SC + 4; // 1092
// vfrag per-batch stride (u16)
constexpr size_t VFRAG_B = (size_t)kW * 32 * 4 * 64 * 8;
}

// ---------------- pack W/bias into bf16 hi/lo planes [640][512] ----------------
__global__ __launch_bounds__(256) void pack_w(
    const float* __restrict__ Wq, const float* __restrict__ bq,
    const float* __restrict__ Wk, const float* __restrict__ bk,
    const float* __restrict__ Wv, const float* __restrict__ bv,
    short* __restrict__ wpk, float* __restrict__ ball) {
  const int r = blockIdx.x;      // 0..639
  const int t = threadIdx.x;     // 256
  const float* src;
  if (r < 64) {
    src = Wq + (size_t)r * kC;
    if (t == 0) ball[r] = bq[r];
  } else if (r < 128) {
    src = Wk + (size_t)(r - 64) * kC;
    if (t == 0) ball[r] = bk[r - 64];
  } else {
    src = Wv + (size_t)(r - 128) * kC;
    if (t == 0) ball[r] = bv[r - 128];
  }
#pragma unroll
  for (int p = 0; p < 2; ++p) {
    const int c = p * 256 + t;
    const float v = src[c];
    const unsigned short h = f32_to_bf16_rn(v);
    const unsigned short l = f32_to_bf16_rn(v - bf16_to_f32(h));
    wpk[(size_t)r * kC + c] = (short)h;
    wpk[(size_t)kO * kC + (size_t)r * kC + c] = (short)l;
  }
}

// ---------------- pack x (one batch): fp32 [c][l] -> bf16 hi/lo [l][c] ----------------
__global__ __launch_bounds__(256) void pack_x(
    const float* __restrict__ x, short* __restrict__ xpk, int b) {
  __shared__ float sT[64][65];
  const int l0 = blockIdx.x * 64;
  const int c0 = blockIdx.y * 64;
  const int t = threadIdx.x;
  const float* xb = x + (size_t)b * kC * kL;
#pragma unroll
  for (int p = 0; p < 4; ++p) {
    const int ch = p * 256 + t;
    const int c = ch >> 4, l4 = (ch & 15) * 4;
    float4 v = *(const float4*)(xb + (size_t)(c0 + c) * kL + l0 + l4);
    sT[c][l4 + 0] = v.x; sT[c][l4 + 1] = v.y; sT[c][l4 + 2] = v.z; sT[c][l4 + 3] = v.w;
  }
  __syncthreads();
#pragma unroll
  for (int p = 0; p < 2; ++p) {
    const int ch = p * 256 + t;
    const int l = ch >> 3, cg = ch & 7;
    short hi[8], lo[8];
#pragma unroll
    for (int j = 0; j < 8; ++j) {
      const float v = sT[cg * 8 + j][l];
      const unsigned short h = f32_to_bf16_rn(v);
      hi[j] = (short)h;
      lo[j] = (short)f32_to_bf16_rn(v - bf16_to_f32(h));
    }
    short* dh = xpk + (size_t)(l0 + l) * kC + c0 + cg * 8;
    *(bf16x8*)dh = *(bf16x8*)hi;
    *(bf16x8*)(dh + (size_t)kL * kC) = *(bf16x8*)lo;
  }
}

// ---------------- projection GEMM via bf16 MFMA, split precision ----------------
__global__ __launch_bounds__(256, 2) void proj_mfma(
    const short* __restrict__ xpk, const short* __restrict__ wpk,
    const float* __restrict__ ball, float* __restrict__ qkv, int b) {
  __shared__ short A_h[128 * 64];
  __shared__ short A_l[128 * 64];
  __shared__ short B_h[128 * 64];
  __shared__ short B_l[128 * 64];
  const int mt = blockIdx.x;          // 0..4
  const int n0 = blockIdx.y * 128;
  const int m0 = mt * 128;
  const bool qk = (mt == 0);
  const int t = threadIdx.x;
  const int wid = t >> 6, lane = t & 63;
  const int wr = wid >> 1, wc = wid & 1;
  const int lr = lane & 15, lg = lane >> 4;
  const int srow8 = lane >> 3;
  const int skg = (lane & 7) ^ srow8;

  f32x4 acc[4][4];
#pragma unroll
  for (int i = 0; i < 4; ++i)
#pragma unroll
    for (int j = 0; j < 4; ++j) acc[i][j] = (f32x4)(0.f);

  for (int kt = 0; kt < 8; ++kt) {
    const int k0 = kt * 64;
#pragma unroll
    for (int p = 0; p < 4; ++p) {
      const int ck = p * 4 + wid;
      const int row = ck * 8 + srow8;
      const short* srcA = wpk + (size_t)(m0 + row) * kC + k0 + skg * 8;
      const short* srcB = xpk + (size_t)(n0 + row) * kC + k0 + skg * 8;
      __builtin_amdgcn_global_load_lds(
          (const __attribute__((address_space(1))) void*)srcA,
          (__attribute__((address_space(3))) void*)&A_h[ck * 512], 16, 0, 0);
      __builtin_amdgcn_global_load_lds(
          (const __attribute__((address_space(1))) void*)(srcA + (size_t)kO * kC),
          (__attribute__((address_space(3))) void*)&A_l[ck * 512], 16, 0, 0);
      __builtin_amdgcn_global_load_lds(
          (const __attribute__((address_space(1))) void*)srcB,
          (__attribute__((address_space(3))) void*)&B_h[ck * 512], 16, 0, 0);
      if (qk)
        __builtin_amdgcn_global_load_lds(
            (const __attribute__((address_space(1))) void*)(srcB + (size_t)kL * kC),
            (__attribute__((address_space(3))) void*)&B_l[ck * 512], 16, 0, 0);
    }
    __syncthreads();
#pragma unroll
    for (int ks = 0; ks < 2; ++ks) {
      bf16x8 ah[4], al[4], bh[4], bl[4];
#pragma unroll
      for (int mf = 0; mf < 4; ++mf) {
        const int row = wr * 64 + mf * 16 + lr;
        const int kg = ks * 4 + lg;
        const int off = row * 64 + ((kg ^ (row & 7)) << 3);
        ah[mf] = *(const bf16x8*)&A_h[off];
        al[mf] = *(const bf16x8*)&A_l[off];
      }
#pragma unroll
      for (int nf = 0; nf < 4; ++nf) {
        const int row = wc * 64 + nf * 16 + lr;
        const int kg = ks * 4 + lg;
        const int off = row * 64 + ((kg ^ (row & 7)) << 3);
        bh[nf] = *(const bf16x8*)&B_h[off];
        if (qk) bl[nf] = *(const bf16x8*)&B_l[off];
      }
#pragma unroll
      for (int mf = 0; mf < 4; ++mf)
#pragma unroll
        for (int nf = 0; nf < 4; ++nf) {
          acc[mf][nf] = __builtin_amdgcn_mfma_f32_16x16x32_bf16(
              ah[mf], bh[nf], acc[mf][nf], 0, 0, 0);
          acc[mf][nf] = __builtin_amdgcn_mfma_f32_16x16x32_bf16(
              al[mf], bh[nf], acc[mf][nf], 0, 0, 0);
          if (qk)
            acc[mf][nf] = __builtin_amdgcn_mfma_f32_16x16x32_bf16(
                ah[mf], bl[nf], acc[mf][nf], 0, 0, 0);
        }
    }
    __syncthreads();
  }
  if (qk) {
    unsigned short* qw = (unsigned short*)qkv + (size_t)b * kO * kL * 2
        + (wr ? KH_OFF : QH_OFF);
#pragma unroll
    for (int mf = 0; mf < 4; ++mf) {
      const int c0 = mf * 16 + lg * 4;
#pragma unroll
      for (int nf = 0; nf < 4; ++nf) {
        const int l = n0 + wc * 64 + nf * 16 + lr;
        unsigned short hi4[4], lo4[4];
#pragma unroll
        for (int r = 0; r < 4; ++r) {
          const float val = acc[mf][nf][r] + ball[wr * 64 + c0 + r];
          const unsigned short h = f32_to_bf16_rn(val);
          hi4[r] = h;
          lo4[r] = f32_to_bf16_rn(val - bf16_to_f32(h));
        }
        unsigned short* d = qw + ((size_t)l * 64 + c0);
        *(uint2*)d = *(uint2*)hi4;
        *(uint2*)(d + QL_OFF) = *(uint2*)lo4;
      }
    }
  } else {
    unsigned short* vbf =
        (unsigned short*)(qkv + ((size_t)b * kO + 128) * kL);
#pragma unroll
    for (int mf = 0; mf < 4; ++mf) {
#pragma unroll
      for (int r = 0; r < 4; ++r) {
        const int m = m0 + wr * 64 + mf * 16 + lg * 4 + r;
        const float bias = ball[m];
        unsigned short* dst = vbf + (size_t)(m - 128) * kL + n0 + wc * 64;
#pragma unroll
        for (int nf = 0; nf < 4; ++nf) {
          dst[nf * 16 + lr] = f32_to_bf16_rn(acc[mf][nf][r] + bias);
        }
      }
    }
  }
}

// ---------------- scores via MFMA, 3-pass split precision ----------------
template <int COL>
__global__ __launch_bounds__(256) void escore_mfma(
    const float* qkv, float* __restrict__ e) {
  const int bi = blockIdx.x;           // b*128 + idx
  const int b = bi >> 7, idx = bi & 127;
  const int t = threadIdx.x;
  const int wid = t >> 6, lane = t & 63;
  const int wj = wid >> 1, wh = wid & 1;
  const int lr = lane & 15, lg = lane >> 4;

  const unsigned short* qkb = (const unsigned short*)qkv + (size_t)b * kO * kL * 2;
  const size_t baseoff = COL ? (size_t)idx * 64 : (size_t)idx * 8192;
  const int rstride = COL ? 8192 : 64;

  f32x4 acc[4][4];
#pragma unroll
  for (int i = 0; i < 4; ++i)
#pragma unroll
    for (int j = 0; j < 4; ++j) acc[i][j] = (f32x4)(0.f);

#pragma unroll
  for (int ks = 0; ks < 2; ++ks) {
    bf16x8 ah[4], al[4], bh[4], bl[4];
#pragma unroll
    for (int mf = 0; mf < 4; ++mf) {
      const size_t ro = baseoff + (size_t)(wj * 64 + mf * 16 + lr) * rstride
          + ks * 32 + lg * 8;
      ah[mf] = *(const bf16x8*)(qkb + KH_OFF + ro);
      al[mf] = *(const bf16x8*)(qkb + KL_OFF + ro);
    }
#pragma unroll
    for (int nf = 0; nf < 4; ++nf) {
      const size_t ro = baseoff + (size_t)(wh * 64 + nf * 16 + lr) * rstride
          + ks * 32 + lg * 8;
      bh[nf] = *(const bf16x8*)(qkb + QH_OFF + ro);
      bl[nf] = *(const bf16x8*)(qkb + QL_OFF + ro);
    }
#pragma unroll
    for (int mf = 0; mf < 4; ++mf)
#pragma unroll
      for (int nf = 0; nf < 4; ++nf) {
        acc[mf][nf] = __builtin_amdgcn_mfma_f32_16x16x32_bf16(
            ah[mf], bh[nf], acc[mf][nf], 0, 0, 0);
        acc[mf][nf] = __builtin_amdgcn_mfma_f32_16x16x32_bf16(
            ah[mf], bl[nf], acc[mf][nf], 0, 0, 0);
        acc[mf][nf] = __builtin_amdgcn_mfma_f32_16x16x32_bf16(
            al[mf], bh[nf], acc[mf][nf], 0, 0, 0);
      }
  }
  const float NEG_INF = __int_as_float(0xff800000);
#pragma unroll
  for (int mf = 0; mf < 4; ++mf) {
    const int row0 = wj * 64 + mf * 16 + lg * 4;     // i or j
#pragma unroll
    for (int nf = 0; nf < 4; ++nf) {
      const int cl = wh * 64 + nf * 16 + lr;          // w or h
      float o[4];
#pragma unroll
      for (int r = 0; r < 4; ++r) {
        float v = acc[mf][nf][r];
        if (COL && (row0 + r == cl)) v = NEG_INF;
        o[r] = v;
      }
      float* dst;
      if (COL)
        dst = e + (((size_t)b * kH + cl) * kW + idx) * 256 + 128 + row0;
      else
        dst = e + (((size_t)b * kH + idx) * kW + cl) * 256 + row0;
      *(float4*)dst = *(const float4*)o;
    }
  }
}

// ---------------- softmax; row half -> bf16 arowT, col half -> bf16 afrag ----
__global__ __launch_bounds__(256) void softmax_kernel(
    float* __restrict__ e, float* qkv_base) {
  const int t = threadIdx.x;
  const int wv = t >> 6, lane = t & 63;
  const size_t pix = (size_t)blockIdx.x * 4 + wv;
  float* p = e + pix * 256 + lane * 4;
  float4 v = *(const float4*)p;
  float m = fmaxf(fmaxf(v.x, v.y), fmaxf(v.z, v.w));
#pragma unroll
  for (int off = 32; off > 0; off >>= 1) m = fmaxf(m, __shfl_xor(m, off, 64));
  float e0 = expf(v.x - m), e1 = expf(v.y - m), e2 = expf(v.z - m), e3 = expf(v.w - m);
  float s = e0 + e1 + e2 + e3;
#pragma unroll
  for (int off = 32; off > 0; off >>= 1) s += __shfl_xor(s, off, 64);
  const float inv = 1.0f / s;
  const float o0 = e0 * inv, o1 = e1 * inv, o2 = e2 * inv, o3 = e3 * inv;
  const int b = (int)(pix >> 14);
  const int h = (int)((pix >> 7) & 127);
  const int w = (int)(pix & 127);
  unsigned short* base = (unsigned short*)qkv_base + (size_t)b * kO * kL * 2;
  if (lane < 32) {
    unsigned short* dst = base + AROWT_OFF + (((size_t)h * kW + w) * 128 + lane * 4);
    *(uint2*)dst = make_uint2(pack_bf16x2(o0, o1), pack_bf16x2(o2, o3));
  } else {
    const int s32 = lane - 32;
    const int jb = s32 >> 3;
    const int lg = (s32 >> 1) & 3;
    const int eoff = (s32 & 1) * 4;
    const int hb = h >> 4, hr = h & 15;
    unsigned short* dst = base + (size_t)w * 16384
        + (((size_t)(jb * 8 + hb) * 64 + lg * 16 + hr) * 8 + eoff);
    *(uint2*)dst = make_uint2(pack_bf16x2(o0, o1), pack_bf16x2(o2, o3));
  }
}

// ---------------- vtrans: vbf bf16 [c][l] -> vfrag bf16 (MFMA A-frag order) ----
__global__ __launch_bounds__(256) void vtrans_kernel(
    const float* __restrict__ qkv, unsigned short* __restrict__ vfrag) {
  __shared__ float sT[16 * VT_SW];   // 69,888 B : [w16][c16][j64]
  const int cb = blockIdx.x;         // 0..31
  const int wt = blockIdx.y;         // 0..7
  const int b  = blockIdx.z;
  const int t = threadIdx.x;
  const int lane = t & 63, wd = t >> 6;
  const int lr = lane & 15, lg = lane >> 4;
  const unsigned short* vb =
      (const unsigned short*)(qkv + ((size_t)b * kO + 128) * kL)
      + (size_t)(cb * 16) * kL + wt * 16;
  unsigned short* vfb = vfrag + (size_t)b * VFRAG_B;

  for (int half = 0; half < 2; ++half) {
    const int j0 = half * 64;
#pragma unroll
    for (int p = 0; p < 16; ++p) {
      const int g = p * 256 + t;
      const int wq = g & 3;
      const int j = (g >> 2) & 63;
      const int ci = p;
      uint2 v2 = *(const uint2*)(vb + (size_t)ci * kL + (size_t)(j0 + j) * kW + wq * 4);
      float* d = sT + ci * VT_SC + j;
      d[(wq * 4 + 0) * VT_SW] = bf16_to_f32((unsigned short)(v2.x & 0xffff));
      d[(wq * 4 + 1) * VT_SW] = bf16_to_f32((unsigned short)(v2.x >> 16));
      d[(wq * 4 + 2) * VT_SW] = bf16_to_f32((unsigned short)(v2.y & 0xffff));
      d[(wq * 4 + 3) * VT_SW] = bf16_to_f32((unsigned short)(v2.y >> 16));
    }
    __syncthreads();
#pragma unroll
    for (int wi = 0; wi < 4; ++wi) {
      const int w = wd * 4 + wi;
#pragma unroll
      for (int ktl = 0; ktl < 2; ++ktl) {
        const float* s = sT + w * VT_SW + lr * VT_SC + ktl * 32 + lg * 8;
        float a[8];
        *(float4*)(a + 0) = *(const float4*)(s + 0);
        *(float4*)(a + 4) = *(const float4*)(s + 4);
        const int ktg = half * 2 + ktl;
        unsigned short* dst = vfb
            + ((((size_t)(wt * 16 + w) * 32 + cb) * 4 + ktg) * 64 + lane) * 8;
        uint4 o = make_uint4(pack_bf16x2(a[0], a[1]), pack_bf16x2(a[2], a[3]),
                             pack_bf16x2(a[4], a[5]), pack_bf16x2(a[6], a[7]));
        *(uint4*)dst = o;
      }
    }
    __syncthreads();
  }
}

// ---------------- col aggregation: direct frag loads; writes bf16 ctmp ----------------
__global__ __launch_bounds__(1024) void colagg_mfma(
    float* qkv, const unsigned short* __restrict__ vfrag) {
  __shared__ float sO[64 * SOC];      // epilogue only
  const int gx = blockIdx.x;          // ct(8) + 8*ht(2)
  const int ct = gx & 7, ht = gx >> 3;
  const int c0 = ct * 64, h0 = ht * 64;
  const int w0 = blockIdx.y * 16;
  const int b = blockIdx.z;
  const int t = threadIdx.x;          // 0..1023
  const int wv = t >> 6, lane = t & 63;
  const int lr = lane & 15, lg = lane >> 4;
  const int w = w0 + wv;

  f32x4 acc[4][4];
#pragma unroll
  for (int i = 0; i < 4; ++i)
#pragma unroll
    for (int j = 0; j < 4; ++j) acc[i][j] = (f32x4)(0.f);

  const unsigned short* ab = (const unsigned short*)qkv + (size_t)b * kO * kL * 2
      + (size_t)w * 16384;
  const unsigned short* vfb = vfrag + (size_t)b * VFRAG_B
      + ((size_t)w * 32 + ct * 4) * 2048;
  unsigned short* ctmp =
      (unsigned short*)(qkv + ((size_t)b * kO + 128) * kL) + CTMP_OFF;

  for (int kt = 0; kt < 4; ++kt) {
    bf16x8 vf[4], af[4];
#pragma unroll
    for (int mf = 0; mf < 4; ++mf)
      vf[mf] = *(const bf16x8*)(vfb + ((size_t)mf * 2048 + kt * 512 + lane * 8));
#pragma unroll
    for (int nf = 0; nf < 4; ++nf)
      af[nf] = *(const bf16x8*)(
          ab + (((size_t)(kt * 8 + ht * 4 + nf) * 64 + lane) * 8));
#pragma unroll
    for (int mf = 0; mf < 4; ++mf)
#pragma unroll
      for (int nf = 0; nf < 4; ++nf)
        acc[mf][nf] = __builtin_amdgcn_mfma_f32_16x16x32_bf16(
            vf[mf], af[nf], acc[mf][nf], 0, 0, 0);
  }

  // ---- epilogue: LDS transpose; uint2 (4w) vectorized ctmp stores ----
  const int ew4 = t & 3, ehh = (t >> 2) & 15, ecb = t >> 6;   // w-quad, h, c-low
  for (int nf = 0; nf < 4; ++nf) {
    __syncthreads();
#pragma unroll
    for (int mf = 0; mf < 4; ++mf)
#pragma unroll
      for (int r = 0; r < 4; ++r)
        sO[(mf * 16 + lg * 4 + r) * SOC + lr * SOW + wv] = acc[mf][nf][r];
    __syncthreads();
#pragma unroll
    for (int q = 0; q < 4; ++q) {
      const int c = q * 16 + ecb;
      const float* s = &sO[c * SOC + ehh * SOW + ew4 * 4];
      unsigned u0 = pack_bf16x2(s[0], s[1]);
      unsigned u1 = pack_bf16x2(s[2], s[3]);
      unsigned short* dst = ctmp + ((size_t)(c0 + c) * kL
          + (size_t)(h0 + nf * 16 + ehh) * kW + w0 + ew4 * 4);
      *(uint2*)dst = make_uint2(u0, u1);
    }
  }
}

// ---------------- row aggregation: direct frags; LDS-transposed vector epilogue ----
// out[b][c][h][w] = ctmp[c][h][w] + sum_i arowT[b][h][w][i] * vbf[c][h*128+i]
__global__ __launch_bounds__(256) void rowagg_mfma(
    const float* qkv, float* __restrict__ out) {
  __shared__ float sO[64 * ROW_SW];   // 33,792 B
  const int ct = blockIdx.x;       // 0..3
  const int bh = blockIdx.y;
  const int b = bh >> 7, h = bh & 127;
  const int c0 = ct * 128;
  const int t = threadIdx.x;
  const int wid = t >> 6, lane = t & 63;
  const int wr = wid >> 1, wc = wid & 1;
  const int lr = lane & 15, lg = lane >> 4;

  f32x4 acc[4][4];
#pragma unroll
  for (int i = 0; i < 4; ++i)
#pragma unroll
    for (int j = 0; j < 4; ++j) acc[i][j] = (f32x4)(0.f);

  const unsigned short* vbf =
      (const unsigned short*)(qkv + ((size_t)b * kO + 128) * kL);
  const unsigned short* ctmp = vbf + CTMP_OFF;
  const unsigned short* arbase = (const unsigned short*)qkv
      + (size_t)b * kO * kL * 2 + AROWT_OFF + (size_t)h * kW * 128;

#pragma unroll
  for (int s = 0; s < 4; ++s) {
    bf16x8 vfr[4], afr[4];
#pragma unroll
    for (int mf = 0; mf < 4; ++mf) {
      const int c = c0 + wr * 64 + mf * 16 + lr;
      vfr[mf] = *(const bf16x8*)(
          vbf + (size_t)c * kL + (size_t)h * kW + s * 32 + lg * 8);
    }
#pragma unroll
    for (int nf = 0; nf < 4; ++nf) {
      const int w = wc * 64 + nf * 16 + lr;
      afr[nf] = *(const bf16x8*)(arbase + (size_t)w * 128 + s * 32 + lg * 8);
    }
#pragma unroll
    for (int mf = 0; mf < 4; ++mf)
#pragma unroll
      for (int nf = 0; nf < 4; ++nf)
        acc[mf][nf] = __builtin_amdgcn_mfma_f32_16x16x32_bf16(
            vfr[mf], afr[nf], acc[mf][nf], 0, 0, 0);
  }

  // ---- epilogue: per c-half, LDS transpose -> float4 stores + uint2 ctmp adds ----
  const int wq = t & 31;            // w-quad index: w = wq*4
  const int cc8 = t >> 5;           // 0..7
  const unsigned short* ctb = ctmp + (size_t)h * kW;
  float* outb = out + ((size_t)b * kC * kL + (size_t)h * kW);
  for (int half = 0; half < 2; ++half) {
    if (wr == half) {
#pragma unroll
      for (int mf = 0; mf < 4; ++mf)
#pragma unroll
        for (int nf = 0; nf < 4; ++nf)
#pragma unroll
          for (int r = 0; r < 4; ++r)
            sO[(mf * 16 + lg * 4 + r) * ROW_SW + wc * 64 + nf * 16 + lr] =
                acc[mf][nf][r];
    }
    __syncthreads();
#pragma unroll
    for (int i = 0; i < 8; ++i) {
      const int cl = i * 8 + cc8;                 // 0..63
      const size_t c = c0 + half * 64 + cl;
      float4 v = *(const float4*)&sO[cl * ROW_SW + wq * 4];
      uint2 c2 = *(const uint2*)(ctb + c * kL + wq * 4);
      v.x += bf16_to_f32((unsigned short)(c2.x & 0xffff));
      v.y += bf16_to_f32((unsigned short)(c2.x >> 16));
      v.z += bf16_to_f32((unsigned short)(c2.y & 0xffff));
      v.w += bf16_to_f32((unsigned short)(c2.y >> 16));
      *(float4*)(outb + c * kL + wq * 4) = v;
    }
    __syncthreads();
  }
}

extern "C" void kernel_launch(void* const* d_in, const int* in_sizes, int n_in,
                              void* d_out, int out_size, void* d_ws, size_t ws_size,
                              hipStream_t stream) {
  (void)in_sizes; (void)n_in; (void)out_size; (void)ws_size;
  const float* x  = (const float*)d_in[0];
  const float* Wq = (const float*)d_in[1];
  const float* bq = (const float*)d_in[2];
  const float* Wk = (const float*)d_in[3];
  const float* bk = (const float*)d_in[4];
  const float* Wv = (const float*)d_in[5];
  const float* bv = (const float*)d_in[6];
  float* out = (float*)d_out;
  float* ws  = (float*)d_ws;

  short* wpk = (short*)(ws + OFF_WALL);
  float* ball = ws + OFF_BALL;
  float* qkv  = ws + OFF_QKV;
  float* e    = ws + OFF_E;
  short* xpk  = (short*)(ws + OFF_E);
  unsigned short* vfrag = (unsigned short*)(ws + OFF_E);

  pack_w<<<dim3(kO), dim3(256), 0, stream>>>(Wq, bq, Wk, bk, Wv, bv, wpk, ball);
  for (int b = 0; b < kB; ++b) {
    pack_x<<<dim3(kL / 64, kC / 64), dim3(256), 0, stream>>>(x, xpk, b);
    proj_mfma<<<dim3(5, kL / 128), dim3(256), 0, stream>>>(xpk, wpk, ball, qkv, b);
  }
  escore_mfma<0><<<dim3(kB * kH), dim3(256), 0, stream>>>(qkv, e);
  escore_mfma<1><<<dim3(kB * kW), dim3(256), 0, stream>>>(qkv, e);
  softmax_kernel<<<dim3(kB * kH * kW / 4), dim3(256), 0, stream>>>(e, qkv);
  vtrans_kernel<<<dim3(32, 8, kB), dim3(256), 0, stream>>>(qkv, vfrag);
  colagg_mfma<<<dim3(16, kW / 16, kB), dim3(1024), 0, stream>>>(qkv, vfrag);
  rowagg_mfma<<<dim3(4, kB * kH), dim3(256), 0, stream>>>(qkv, out);
}

// Round 14
// 397.866 us; speedup vs baseline: 1.2428x; 1.0454x over previous
//
#include <hip/hip_runtime.h>
#include <hip/hip_bf16.h>

namespace {
constexpr int kB = 4;
constexpr int kC = 512;
constexpr int kH = 128;
constexpr int kW = 128;
constexpr int kCQK = 64;
constexpr int kL = kH * kW;   // 16384
constexpr int kO = 640;       // rows: [0,64)=Wq, [64,128)=Wk, [128,640)=Wv

// workspace layout (float offsets)
constexpr size_t OFF_WALL = 0;                          // wpk: 640*512*2 bf16
constexpr size_t OFF_BALL = (size_t)kO * kC;            // 640
constexpr size_t OFF_QKV  = OFF_BALL + kO;              // B*640*L region
constexpr size_t OFF_E    = OFF_QKV + (size_t)kB * kO * kL;  // B*H*W*256 fp32
constexpr size_t WS_FLOATS = OFF_E + (size_t)kB * kH * kW * 256;
// Optional (if ws_size permits): xpk_all bf16 at ws+WS_FLOATS, 4 batches x 67MB/2.
// Per-batch q/k region (first 128 fp32-rows = 8.4MB/b):
//   proj writes qkb bf16 planes: qh@0, ql@1M, kh@2M, kl@3M (u16 offsets)
//   escore reads qkb; softmax overwrites with afrag[0,2M) + arowT[2M,4M)
// Per-batch v region (rows 128..640, 33.5MB/b), as u16:
//   [0 .. 8.4M)     vbf[c 512][l 16384] bf16   (proj)
//   [8.4M .. 16.8M) lifecycle: qkbT planes qhT/qlT/khT/klT [w][h][c] (proj->escore_col)
//                   then ctmp[c 512][h 128][w 128] bf16 (colagg -> rowagg)
// e region (67MB): xpk-fallback (pre-proj) -> scores fp32 -> vfrag bf16

typedef __attribute__((ext_vector_type(8))) short bf16x8;
typedef __attribute__((ext_vector_type(4))) float f32x4;

__device__ __forceinline__ unsigned short f32_to_bf16_rn(float f) {
  unsigned u = __float_as_uint(f);
  unsigned r = (u + 0x7FFFu + ((u >> 16) & 1u)) >> 16;
  return (unsigned short)r;
}
__device__ __forceinline__ float bf16_to_f32(unsigned short h) {
  return __uint_as_float(((unsigned)h) << 16);
}
__device__ __forceinline__ unsigned pack_bf16x2(float a, float b) {
  return (unsigned)f32_to_bf16_rn(a) | ((unsigned)f32_to_bf16_rn(b) << 16);
}
// colagg epilogue sO strides (f32 units): [c 64][h 16][w 16]
constexpr int SOW = 17;
constexpr int SOC = 16 * SOW + 1;   // 273
// rowagg epilogue sO strides (f32 units): [c 64][w 128(+4)]
constexpr int ROW_SW = 132;
constexpr size_t AROWT_OFF = 2097152;   // u16 offset within q/k region
// qkb plane offsets (u16, within batch q/k region)
constexpr size_t QH_OFF = 0;
constexpr size_t QL_OFF = 1048576;
constexpr size_t KH_OFF = 2097152;
constexpr size_t KL_OFF = 3145728;
// v-region u16 offsets: qkbT planes / ctmp share [8.4M,16.8M)
constexpr size_t CTMP_OFF = 8388608;
// vtrans LDS strides (f32 units)
constexpr int VT_SC = 68;
constexpr int VT_SW = 16 * VT_SC + 4; // 1092
// vfrag per-batch stride (u16)
constexpr size_t VFRAG_B = (size_t)kW * 32 * 4 * 64 * 8;
}

// ---------------- pack W/bias into bf16 hi/lo planes [640][512] ----------------
__global__ __launch_bounds__(256) void pack_w(
    const float* __restrict__ Wq, const float* __restrict__ bq,
    const float* __restrict__ Wk, const float* __restrict__ bk,
    const float* __restrict__ Wv, const float* __restrict__ bv,
    short* __restrict__ wpk, float* __restrict__ ball) {
  const int r = blockIdx.x;      // 0..639
  const int t = threadIdx.x;     // 256
  const float* src;
  if (r < 64) {
    src = Wq + (size_t)r * kC;
    if (t == 0) ball[r] = bq[r];
  } else if (r < 128) {
    src = Wk + (size_t)(r - 64) * kC;
    if (t == 0) ball[r] = bk[r - 64];
  } else {
    src = Wv + (size_t)(r - 128) * kC;
    if (t == 0) ball[r] = bv[r - 128];
  }
#pragma unroll
  for (int p = 0; p < 2; ++p) {
    const int c = p * 256 + t;
    const float v = src[c];
    const unsigned short h = f32_to_bf16_rn(v);
    const unsigned short l = f32_to_bf16_rn(v - bf16_to_f32(h));
    wpk[(size_t)r * kC + c] = (short)h;
    wpk[(size_t)kO * kC + (size_t)r * kC + c] = (short)l;
  }
}

// ---------------- pack x: fp32 [c][l] -> bf16 hi/lo [l][c]; batch = b_off+z ----
__global__ __launch_bounds__(256) void pack_x(
    const float* __restrict__ x, short* __restrict__ xpk,
    int b_off, size_t xstride) {
  __shared__ float sT[64][65];
  const int l0 = blockIdx.x * 64;
  const int c0 = blockIdx.y * 64;
  const int b = b_off + blockIdx.z;
  const int t = threadIdx.x;
  const float* xb = x + (size_t)b * kC * kL;
  short* xo = xpk + (size_t)blockIdx.z * xstride;
#pragma unroll
  for (int p = 0; p < 4; ++p) {
    const int ch = p * 256 + t;
    const int c = ch >> 4, l4 = (ch & 15) * 4;
    float4 v = *(const float4*)(xb + (size_t)(c0 + c) * kL + l0 + l4);
    sT[c][l4 + 0] = v.x; sT[c][l4 + 1] = v.y; sT[c][l4 + 2] = v.z; sT[c][l4 + 3] = v.w;
  }
  __syncthreads();
#pragma unroll
  for (int p = 0; p < 2; ++p) {
    const int ch = p * 256 + t;
    const int l = ch >> 3, cg = ch & 7;
    short hi[8], lo[8];
#pragma unroll
    for (int j = 0; j < 8; ++j) {
      const float v = sT[cg * 8 + j][l];
      const unsigned short h = f32_to_bf16_rn(v);
      hi[j] = (short)h;
      lo[j] = (short)f32_to_bf16_rn(v - bf16_to_f32(h));
    }
    short* dh = xo + (size_t)(l0 + l) * kC + c0 + cg * 8;
    *(bf16x8*)dh = *(bf16x8*)hi;
    *(bf16x8*)(dh + (size_t)kL * kC) = *(bf16x8*)lo;
  }
}

// ---------------- projection GEMM via bf16 MFMA, split precision ----------------
// batch = b_off + blockIdx.z (xpk indexed by blockIdx.z * xstride).
// qk tile (mt==0) -> qkb planes [h][w][c] AND transposed qkbT planes [w][h][c].
__global__ __launch_bounds__(256, 2) void proj_mfma(
    const short* __restrict__ xpk, size_t xstride,
    const short* __restrict__ wpk,
    const float* __restrict__ ball, float* __restrict__ qkv, int b_off) {
  __shared__ short A_h[128 * 64];
  __shared__ short A_l[128 * 64];
  __shared__ short B_h[128 * 64];
  __shared__ short B_l[128 * 64];
  const int mt = blockIdx.x;          // 0..4
  const int n0 = blockIdx.y * 128;
  const int m0 = mt * 128;
  const int b = b_off + blockIdx.z;
  const bool qk = (mt == 0);
  const int t = threadIdx.x;
  const int wid = t >> 6, lane = t & 63;
  const int wr = wid >> 1, wc = wid & 1;
  const int lr = lane & 15, lg = lane >> 4;
  const int srow8 = lane >> 3;
  const int skg = (lane & 7) ^ srow8;
  const short* xo = xpk + (size_t)blockIdx.z * xstride;

  f32x4 acc[4][4];
#pragma unroll
  for (int i = 0; i < 4; ++i)
#pragma unroll
    for (int j = 0; j < 4; ++j) acc[i][j] = (f32x4)(0.f);

  for (int kt = 0; kt < 8; ++kt) {
    const int k0 = kt * 64;
#pragma unroll
    for (int p = 0; p < 4; ++p) {
      const int ck = p * 4 + wid;
      const int row = ck * 8 + srow8;
      const short* srcA = wpk + (size_t)(m0 + row) * kC + k0 + skg * 8;
      const short* srcB = xo + (size_t)(n0 + row) * kC + k0 + skg * 8;
      __builtin_amdgcn_global_load_lds(
          (const __attribute__((address_space(1))) void*)srcA,
          (__attribute__((address_space(3))) void*)&A_h[ck * 512], 16, 0, 0);
      __builtin_amdgcn_global_load_lds(
          (const __attribute__((address_space(1))) void*)(srcA + (size_t)kO * kC),
          (__attribute__((address_space(3))) void*)&A_l[ck * 512], 16, 0, 0);
      __builtin_amdgcn_global_load_lds(
          (const __attribute__((address_space(1))) void*)srcB,
          (__attribute__((address_space(3))) void*)&B_h[ck * 512], 16, 0, 0);
      if (qk)
        __builtin_amdgcn_global_load_lds(
            (const __attribute__((address_space(1))) void*)(srcB + (size_t)kL * kC),
            (__attribute__((address_space(3))) void*)&B_l[ck * 512], 16, 0, 0);
    }
    __syncthreads();
#pragma unroll
    for (int ks = 0; ks < 2; ++ks) {
      bf16x8 ah[4], al[4], bh[4], bl[4];
#pragma unroll
      for (int mf = 0; mf < 4; ++mf) {
        const int row = wr * 64 + mf * 16 + lr;
        const int kg = ks * 4 + lg;
        const int off = row * 64 + ((kg ^ (row & 7)) << 3);
        ah[mf] = *(const bf16x8*)&A_h[off];
        al[mf] = *(const bf16x8*)&A_l[off];
      }
#pragma unroll
      for (int nf = 0; nf < 4; ++nf) {
        const int row = wc * 64 + nf * 16 + lr;
        const int kg = ks * 4 + lg;
        const int off = row * 64 + ((kg ^ (row & 7)) << 3);
        bh[nf] = *(const bf16x8*)&B_h[off];
        if (qk) bl[nf] = *(const bf16x8*)&B_l[off];
      }
#pragma unroll
      for (int mf = 0; mf < 4; ++mf)
#pragma unroll
        for (int nf = 0; nf < 4; ++nf) {
          acc[mf][nf] = __builtin_amdgcn_mfma_f32_16x16x32_bf16(
              ah[mf], bh[nf], acc[mf][nf], 0, 0, 0);
          acc[mf][nf] = __builtin_amdgcn_mfma_f32_16x16x32_bf16(
              al[mf], bh[nf], acc[mf][nf], 0, 0, 0);
          if (qk)
            acc[mf][nf] = __builtin_amdgcn_mfma_f32_16x16x32_bf16(
                ah[mf], bl[nf], acc[mf][nf], 0, 0, 0);
        }
    }
    __syncthreads();
  }
  if (qk) {
    unsigned short* qw = (unsigned short*)qkv + (size_t)b * kO * kL * 2
        + (wr ? KH_OFF : QH_OFF);
    unsigned short* tb = (unsigned short*)(qkv + ((size_t)b * kO + 128) * kL)
        + CTMP_OFF + (wr ? 2097152 : 0);   // qhT/khT; lo plane at +1048576
#pragma unroll
    for (int mf = 0; mf < 4; ++mf) {
      const int c0 = mf * 16 + lg * 4;
#pragma unroll
      for (int nf = 0; nf < 4; ++nf) {
        const int l = n0 + wc * 64 + nf * 16 + lr;
        unsigned short hi4[4], lo4[4];
#pragma unroll
        for (int r = 0; r < 4; ++r) {
          const float val = acc[mf][nf][r] + ball[wr * 64 + c0 + r];
          const unsigned short h = f32_to_bf16_rn(val);
          hi4[r] = h;
          lo4[r] = f32_to_bf16_rn(val - bf16_to_f32(h));
        }
        unsigned short* d = qw + ((size_t)l * 64 + c0);
        *(uint2*)d = *(uint2*)hi4;
        *(uint2*)(d + QL_OFF) = *(uint2*)lo4;
        // transposed copy: [w][h][c]
        const int hh = l >> 7, ww = l & 127;
        unsigned short* dT = tb + (((size_t)ww * 128 + hh) * 64 + c0);
        *(uint2*)dT = *(uint2*)hi4;
        *(uint2*)(dT + 1048576) = *(uint2*)lo4;
      }
    }
  } else {
    unsigned short* vbf =
        (unsigned short*)(qkv + ((size_t)b * kO + 128) * kL);
#pragma unroll
    for (int mf = 0; mf < 4; ++mf) {
#pragma unroll
      for (int r = 0; r < 4; ++r) {
        const int m = m0 + wr * 64 + mf * 16 + lg * 4 + r;
        const float bias = ball[m];
        unsigned short* dst = vbf + (size_t)(m - 128) * kL + n0 + wc * 64;
#pragma unroll
        for (int nf = 0; nf < 4; ++nf) {
          dst[nf * 16 + lr] = f32_to_bf16_rn(acc[mf][nf][r] + bias);
        }
      }
    }
  }
}

// ---------------- scores via MFMA, 3-pass split precision ----------------
// Both variants read [idx][row][c]-contiguous planes (rstride 64, coalesced).
// ROW: idx=h, row=i(k)/w(q), planes = qkb.  COL: idx=w, row=j(k)/h(q), planes = qkbT.
template <int COL>
__global__ __launch_bounds__(256) void escore_mfma(
    const unsigned short* __restrict__ qh, const unsigned short* __restrict__ ql,
    const unsigned short* __restrict__ kh, const unsigned short* __restrict__ kl,
    float* __restrict__ e) {
  const int bi = blockIdx.x;           // b*128 + idx
  const int b = bi >> 7, idx = bi & 127;
  const int t = threadIdx.x;
  const int wid = t >> 6, lane = t & 63;
  const int wj = wid >> 1, wh = wid & 1;
  const int lr = lane & 15, lg = lane >> 4;

  const size_t base = (size_t)b * ((size_t)kO * kL * 2) + (size_t)idx * 8192;

  f32x4 acc[4][4];
#pragma unroll
  for (int i = 0; i < 4; ++i)
#pragma unroll
    for (int j = 0; j < 4; ++j) acc[i][j] = (f32x4)(0.f);

#pragma unroll
  for (int ks = 0; ks < 2; ++ks) {
    bf16x8 ah[4], al[4], bh[4], bl[4];
#pragma unroll
    for (int mf = 0; mf < 4; ++mf) {
      const size_t ro = base + (size_t)(wj * 64 + mf * 16 + lr) * 64
          + ks * 32 + lg * 8;
      ah[mf] = *(const bf16x8*)(kh + ro);
      al[mf] = *(const bf16x8*)(kl + ro);
    }
#pragma unroll
    for (int nf = 0; nf < 4; ++nf) {
      const size_t ro = base + (size_t)(wh * 64 + nf * 16 + lr) * 64
          + ks * 32 + lg * 8;
      bh[nf] = *(const bf16x8*)(qh + ro);
      bl[nf] = *(const bf16x8*)(ql + ro);
    }
#pragma unroll
    for (int mf = 0; mf < 4; ++mf)
#pragma unroll
      for (int nf = 0; nf < 4; ++nf) {
        acc[mf][nf] = __builtin_amdgcn_mfma_f32_16x16x32_bf16(
            ah[mf], bh[nf], acc[mf][nf], 0, 0, 0);
        acc[mf][nf] = __builtin_amdgcn_mfma_f32_16x16x32_bf16(
            ah[mf], bl[nf], acc[mf][nf], 0, 0, 0);
        acc[mf][nf] = __builtin_amdgcn_mfma_f32_16x16x32_bf16(
            al[mf], bh[nf], acc[mf][nf], 0, 0, 0);
      }
  }
  const float NEG_INF = __int_as_float(0xff800000);
#pragma unroll
  for (int mf = 0; mf < 4; ++mf) {
    const int row0 = wj * 64 + mf * 16 + lg * 4;     // i or j
#pragma unroll
    for (int nf = 0; nf < 4; ++nf) {
      const int cl = wh * 64 + nf * 16 + lr;          // w or h
      float o[4];
#pragma unroll
      for (int r = 0; r < 4; ++r) {
        float v = acc[mf][nf][r];
        if (COL && (row0 + r == cl)) v = NEG_INF;
        o[r] = v;
      }
      float* dst;
      if (COL)
        dst = e + (((size_t)b * kH + cl) * kW + idx) * 256 + 128 + row0;
      else
        dst = e + (((size_t)b * kH + idx) * kW + cl) * 256 + row0;
      *(float4*)dst = *(const float4*)o;
    }
  }
}

// ---------------- softmax; row half -> bf16 arowT, col half -> bf16 afrag ----
__global__ __launch_bounds__(256) void softmax_kernel(
    float* __restrict__ e, float* qkv_base) {
  const int t = threadIdx.x;
  const int wv = t >> 6, lane = t & 63;
  const size_t pix = (size_t)blockIdx.x * 4 + wv;
  float* p = e + pix * 256 + lane * 4;
  float4 v = *(const float4*)p;
  float m = fmaxf(fmaxf(v.x, v.y), fmaxf(v.z, v.w));
#pragma unroll
  for (int off = 32; off > 0; off >>= 1) m = fmaxf(m, __shfl_xor(m, off, 64));
  float e0 = expf(v.x - m), e1 = expf(v.y - m), e2 = expf(v.z - m), e3 = expf(v.w - m);
  float s = e0 + e1 + e2 + e3;
#pragma unroll
  for (int off = 32; off > 0; off >>= 1) s += __shfl_xor(s, off, 64);
  const float inv = 1.0f / s;
  const float o0 = e0 * inv, o1 = e1 * inv, o2 = e2 * inv, o3 = e3 * inv;
  const int b = (int)(pix >> 14);
  const int h = (int)((pix >> 7) & 127);
  const int w = (int)(pix & 127);
  unsigned short* base = (unsigned short*)qkv_base + (size_t)b * kO * kL * 2;
  if (lane < 32) {
    unsigned short* dst = base + AROWT_OFF + (((size_t)h * kW + w) * 128 + lane * 4);
    *(uint2*)dst = make_uint2(pack_bf16x2(o0, o1), pack_bf16x2(o2, o3));
  } else {
    const int s32 = lane - 32;
    const int jb = s32 >> 3;
    const int lg = (s32 >> 1) & 3;
    const int eoff = (s32 & 1) * 4;
    const int hb = h >> 4, hr = h & 15;
    unsigned short* dst = base + (size_t)w * 16384
        + (((size_t)(jb * 8 + hb) * 64 + lg * 16 + hr) * 8 + eoff);
    *(uint2*)dst = make_uint2(pack_bf16x2(o0, o1), pack_bf16x2(o2, o3));
  }
}

// ---------------- vtrans: vbf bf16 [c][l] -> vfrag bf16 (MFMA A-frag order) ----
__global__ __launch_bounds__(256) void vtrans_kernel(
    const float* __restrict__ qkv, unsigned short* __restrict__ vfrag) {
  __shared__ float sT[16 * VT_SW];   // 69,888 B : [w16][c16][j64]
  const int cb = blockIdx.x;         // 0..31
  const int wt = blockIdx.y;         // 0..7
  const int b  = blockIdx.z;
  const int t = threadIdx.x;
  const int lane = t & 63, wd = t >> 6;
  const int lr = lane & 15, lg = lane >> 4;
  const unsigned short* vb =
      (const unsigned short*)(qkv + ((size_t)b * kO + 128) * kL)
      + (size_t)(cb * 16) * kL + wt * 16;
  unsigned short* vfb = vfrag + (size_t)b * VFRAG_B;

  for (int half = 0; half < 2; ++half) {
    const int j0 = half * 64;
#pragma unroll
    for (int p = 0; p < 16; ++p) {
      const int g = p * 256 + t;
      const int wq = g & 3;
      const int j = (g >> 2) & 63;
      const int ci = p;
      uint2 v2 = *(const uint2*)(vb + (size_t)ci * kL + (size_t)(j0 + j) * kW + wq * 4);
      float* d = sT + ci * VT_SC + j;
      d[(wq * 4 + 0) * VT_SW] = bf16_to_f32((unsigned short)(v2.x & 0xffff));
      d[(wq * 4 + 1) * VT_SW] = bf16_to_f32((unsigned short)(v2.x >> 16));
      d[(wq * 4 + 2) * VT_SW] = bf16_to_f32((unsigned short)(v2.y & 0xffff));
      d[(wq * 4 + 3) * VT_SW] = bf16_to_f32((unsigned short)(v2.y >> 16));
    }
    __syncthreads();
#pragma unroll
    for (int wi = 0; wi < 4; ++wi) {
      const int w = wd * 4 + wi;
#pragma unroll
      for (int ktl = 0; ktl < 2; ++ktl) {
        const float* s = sT + w * VT_SW + lr * VT_SC + ktl * 32 + lg * 8;
        float a[8];
        *(float4*)(a + 0) = *(const float4*)(s + 0);
        *(float4*)(a + 4) = *(const float4*)(s + 4);
        const int ktg = half * 2 + ktl;
        unsigned short* dst = vfb
            + ((((size_t)(wt * 16 + w) * 32 + cb) * 4 + ktg) * 64 + lane) * 8;
        uint4 o = make_uint4(pack_bf16x2(a[0], a[1]), pack_bf16x2(a[2], a[3]),
                             pack_bf16x2(a[4], a[5]), pack_bf16x2(a[6], a[7]));
        *(uint4*)dst = o;
      }
    }
    __syncthreads();
  }
}

// ---------------- col aggregation: direct frag loads; writes bf16 ctmp ----------------
__global__ __launch_bounds__(1024) void colagg_mfma(
    float* qkv, const unsigned short* __restrict__ vfrag) {
  __shared__ float sO[64 * SOC];      // epilogue only
  const int gx = blockIdx.x;          // ct(8) + 8*ht(2)
  const int ct = gx & 7, ht = gx >> 3;
  const int c0 = ct * 64, h0 = ht * 64;
  const int w0 = blockIdx.y * 16;
  const int b = blockIdx.z;
  const int t = threadIdx.x;          // 0..1023
  const int wv = t >> 6, lane = t & 63;
  const int lr = lane & 15, lg = lane >> 4;
  const int w = w0 + wv;

  f32x4 acc[4][4];
#pragma unroll
  for (int i = 0; i < 4; ++i)
#pragma unroll
    for (int j = 0; j < 4; ++j) acc[i][j] = (f32x4)(0.f);

  const unsigned short* ab = (const unsigned short*)qkv + (size_t)b * kO * kL * 2
      + (size_t)w * 16384;
  const unsigned short* vfb = vfrag + (size_t)b * VFRAG_B
      + ((size_t)w * 32 + ct * 4) * 2048;
  unsigned short* ctmp =
      (unsigned short*)(qkv + ((size_t)b * kO + 128) * kL) + CTMP_OFF;

  for (int kt = 0; kt < 4; ++kt) {
    bf16x8 vf[4], af[4];
#pragma unroll
    for (int mf = 0; mf < 4; ++mf)
      vf[mf] = *(const bf16x8*)(vfb + ((size_t)mf * 2048 + kt * 512 + lane * 8));
#pragma unroll
    for (int nf = 0; nf < 4; ++nf)
      af[nf] = *(const bf16x8*)(
          ab + (((size_t)(kt * 8 + ht * 4 + nf) * 64 + lane) * 8));
#pragma unroll
    for (int mf = 0; mf < 4; ++mf)
#pragma unroll
      for (int nf = 0; nf < 4; ++nf)
        acc[mf][nf] = __builtin_amdgcn_mfma_f32_16x16x32_bf16(
            vf[mf], af[nf], acc[mf][nf], 0, 0, 0);
  }

  // ---- epilogue: LDS transpose; uint2 (4w) vectorized ctmp stores ----
  const int ew4 = t & 3, ehh = (t >> 2) & 15, ecb = t >> 6;   // w-quad, h, c-low
  for (int nf = 0; nf < 4; ++nf) {
    __syncthreads();
#pragma unroll
    for (int mf = 0; mf < 4; ++mf)
#pragma unroll
      for (int r = 0; r < 4; ++r)
        sO[(mf * 16 + lg * 4 + r) * SOC + lr * SOW + wv] = acc[mf][nf][r];
    __syncthreads();
#pragma unroll
    for (int q = 0; q < 4; ++q) {
      const int c = q * 16 + ecb;
      const float* s = &sO[c * SOC + ehh * SOW + ew4 * 4];
      unsigned u0 = pack_bf16x2(s[0], s[1]);
      unsigned u1 = pack_bf16x2(s[2], s[3]);
      unsigned short* dst = ctmp + ((size_t)(c0 + c) * kL
          + (size_t)(h0 + nf * 16 + ehh) * kW + w0 + ew4 * 4);
      *(uint2*)dst = make_uint2(u0, u1);
    }
  }
}

// ---------------- row aggregation: direct frags; LDS-transposed vector epilogue ----
__global__ __launch_bounds__(256) void rowagg_mfma(
    const float* qkv, float* __restrict__ out) {
  __shared__ float sO[64 * ROW_SW];   // 33,792 B
  const int ct = blockIdx.x;       // 0..3
  const int bh = blockIdx.y;
  const int b = bh >> 7, h = bh & 127;
  const int c0 = ct * 128;
  const int t = threadIdx.x;
  const int wid = t >> 6, lane = t & 63;
  const int wr = wid >> 1, wc = wid & 1;
  const int lr = lane & 15, lg = lane >> 4;

  f32x4 acc[4][4];
#pragma unroll
  for (int i = 0; i < 4; ++i)
#pragma unroll
    for (int j = 0; j < 4; ++j) acc[i][j] = (f32x4)(0.f);

  const unsigned short* vbf =
      (const unsigned short*)(qkv + ((size_t)b * kO + 128) * kL);
  const unsigned short* ctmp = vbf + CTMP_OFF;
  const unsigned short* arbase = (const unsigned short*)qkv
      + (size_t)b * kO * kL * 2 + AROWT_OFF + (size_t)h * kW * 128;

#pragma unroll
  for (int s = 0; s < 4; ++s) {
    bf16x8 vfr[4], afr[4];
#pragma unroll
    for (int mf = 0; mf < 4; ++mf) {
      const int c = c0 + wr * 64 + mf * 16 + lr;
      vfr[mf] = *(const bf16x8*)(
          vbf + (size_t)c * kL + (size_t)h * kW + s * 32 + lg * 8);
    }
#pragma unroll
    for (int nf = 0; nf < 4; ++nf) {
      const int w = wc * 64 + nf * 16 + lr;
      afr[nf] = *(const bf16x8*)(arbase + (size_t)w * 128 + s * 32 + lg * 8);
    }
#pragma unroll
    for (int mf = 0; mf < 4; ++mf)
#pragma unroll
      for (int nf = 0; nf < 4; ++nf)
        acc[mf][nf] = __builtin_amdgcn_mfma_f32_16x16x32_bf16(
            vfr[mf], afr[nf], acc[mf][nf], 0, 0, 0);
  }

  // ---- epilogue: per c-half, LDS transpose -> float4 stores + uint2 ctmp adds ----
  const int wq = t & 31;            // w-quad index: w = wq*4
  const int cc8 = t >> 5;           // 0..7
  const unsigned short* ctb = ctmp + (size_t)h * kW;
  float* outb = out + ((size_t)b * kC * kL + (size_t)h * kW);
  for (int half = 0; half < 2; ++half) {
    if (wr == half) {
#pragma unroll
      for (int mf = 0; mf < 4; ++mf)
#pragma unroll
        for (int nf = 0; nf < 4; ++nf)
#pragma unroll
          for (int r = 0; r < 4; ++r)
            sO[(mf * 16 + lg * 4 + r) * ROW_SW + wc * 64 + nf * 16 + lr] =
                acc[mf][nf][r];
    }
    __syncthreads();
#pragma unroll
    for (int i = 0; i < 8; ++i) {
      const int cl = i * 8 + cc8;                 // 0..63
      const size_t c = c0 + half * 64 + cl;
      float4 v = *(const float4*)&sO[cl * ROW_SW + wq * 4];
      uint2 c2 = *(const uint2*)(ctb + c * kL + wq * 4);
      v.x += bf16_to_f32((unsigned short)(c2.x & 0xffff));
      v.y += bf16_to_f32((unsigned short)(c2.x >> 16));
      v.z += bf16_to_f32((unsigned short)(c2.y & 0xffff));
      v.w += bf16_to_f32((unsigned short)(c2.y >> 16));
      *(float4*)(outb + c * kL + wq * 4) = v;
    }
    __syncthreads();
  }
}

extern "C" void kernel_launch(void* const* d_in, const int* in_sizes, int n_in,
                              void* d_out, int out_size, void* d_ws, size_t ws_size,
                              hipStream_t stream) {
  (void)in_sizes; (void)n_in; (void)out_size;
  const float* x  = (const float*)d_in[0];
  const float* Wq = (const float*)d_in[1];
  const float* bq = (const float*)d_in[2];
  const float* Wk = (const float*)d_in[3];
  const float* bk = (const float*)d_in[4];
  const float* Wv = (const float*)d_in[5];
  const float* bv = (const float*)d_in[6];
  float* out = (float*)d_out;
  float* ws  = (float*)d_ws;

  short* wpk = (short*)(ws + OFF_WALL);
  float* ball = ws + OFF_BALL;
  float* qkv  = ws + OFF_QKV;
  float* e    = ws + OFF_E;
  unsigned short* vfrag = (unsigned short*)(ws + OFF_E);

  pack_w<<<dim3(kO), dim3(256), 0, stream>>>(Wq, bq, Wk, bk, Wv, bv, wpk, ball);

  const size_t xpk_batch = (size_t)2 * kL * kC;             // shorts per batch
  const size_t need = WS_FLOATS * sizeof(float)
      + (size_t)kB * xpk_batch * sizeof(short);
  if (ws_size >= need) {
    // all-batch xpk in spare workspace -> single fused pack/proj launches
    short* xall = (short*)(ws + WS_FLOATS);
    pack_x<<<dim3(kL / 64, kC / 64, kB), dim3(256), 0, stream>>>(
        x, xall, 0, xpk_batch);
    proj_mfma<<<dim3(5, kL / 128, kB), dim3(256), 0, stream>>>(
        xall, xpk_batch, wpk, ball, qkv, 0);
  } else {
    // fallback: per-batch xpk aliased into e region
    short* xpk = (short*)(ws + OFF_E);
    for (int b = 0; b < kB; ++b) {
      pack_x<<<dim3(kL / 64, kC / 64, 1), dim3(256), 0, stream>>>(x, xpk, b, 0);
      proj_mfma<<<dim3(5, kL / 128, 1), dim3(256), 0, stream>>>(
          xpk, 0, wpk, ball, qkv, b);
    }
  }

  unsigned short* qkb0 = (unsigned short*)qkv;
  escore_mfma<0><<<dim3(kB * kH), dim3(256), 0, stream>>>(
      qkb0 + QH_OFF, qkb0 + QL_OFF, qkb0 + KH_OFF, qkb0 + KL_OFF, e);
  unsigned short* vt0 = (unsigned short*)qkv + (size_t)128 * kL * 2 + CTMP_OFF;
  escore_mfma<1><<<dim3(kB * kW), dim3(256), 0, stream>>>(
      vt0 + 0, vt0 + 1048576, vt0 + 2097152, vt0 + 3145728, e);
  softmax_kernel<<<dim3(kB * kH * kW / 4), dim3(256), 0, stream>>>(e, qkv);
  vtrans_kernel<<<dim3(32, 8, kB), dim3(256), 0, stream>>>(qkv, vfrag);
  colagg_mfma<<<dim3(16, kW / 16, kB), dim3(1024), 0, stream>>>(qkv, vfrag);
  rowagg_mfma<<<dim3(4, kB * kH), dim3(256), 0, stream>>>(qkv, out);
}

// Round 15
// 394.015 us; speedup vs baseline: 1.2550x; 1.0098x over previous
//
#include <hip/hip_runtime.h>
#include <hip/hip_bf16.h>

namespace {
constexpr int kB = 4;
constexpr int kC = 512;
constexpr int kH = 128;
constexpr int kW = 128;
constexpr int kL = kH * kW;   // 16384
constexpr int kO = 640;

// workspace layout (float offsets)
constexpr size_t OFF_WALL = 0;
constexpr size_t OFF_BALL = (size_t)kO * kC;
constexpr size_t OFF_QKV  = OFF_BALL + kO;
constexpr size_t OFF_E    = OFF_QKV + (size_t)kB * kO * kL;
constexpr size_t WS_FLOATS = OFF_E + (size_t)kB * kH * kW * 256;
// q/k region per batch (8.4MB): qkb planes qh@0 ql@1M kh@2M kl@3M (u16),
//   later overwritten by softmax: afrag[0,2M) + arowT[2M,4M)
// v region per batch (33.5MB): vbf[c][l] bf16 [0,8.4M); [8.4M,16.8M) holds
//   qkbT planes (qktrans -> escore_col), then ctmp (colagg -> rowagg)
// e region (67MB): xpk-fallback -> scores fp32 -> vfrag bf16

typedef __attribute__((ext_vector_type(8))) short bf16x8;
typedef __attribute__((ext_vector_type(4))) float f32x4;

__device__ __forceinline__ unsigned short f32_to_bf16_rn(float f) {
  unsigned u = __float_as_uint(f);
  unsigned r = (u + 0x7FFFu + ((u >> 16) & 1u)) >> 16;
  return (unsigned short)r;
}
__device__ __forceinline__ float bf16_to_f32(unsigned short h) {
  return __uint_as_float(((unsigned)h) << 16);
}
__device__ __forceinline__ unsigned pack_bf16x2(float a, float b) {
  return (unsigned)f32_to_bf16_rn(a) | ((unsigned)f32_to_bf16_rn(b) << 16);
}
constexpr int SOW = 17;
constexpr int SOC = 16 * SOW + 1;   // 273
constexpr int ROW_SW = 132;
constexpr size_t AROWT_OFF = 2097152;
constexpr size_t QH_OFF = 0;
constexpr size_t QL_OFF = 1048576;
constexpr size_t KH_OFF = 2097152;
constexpr size_t KL_OFF = 3145728;
constexpr size_t CTMP_OFF = 8388608;
constexpr int VT_SC = 68;
constexpr int VT_SW = 16 * VT_SC + 4;
constexpr size_t VFRAG_B = (size_t)kW * 32 * 4 * 64 * 8;
}

// ---------------- pack W/bias into bf16 hi/lo planes [640][512] ----------------
__global__ __launch_bounds__(256) void pack_w(
    const float* __restrict__ Wq, const float* __restrict__ bq,
    const float* __restrict__ Wk, const float* __restrict__ bk,
    const float* __restrict__ Wv, const float* __restrict__ bv,
    short* __restrict__ wpk, float* __restrict__ ball) {
  const int r = blockIdx.x;
  const int t = threadIdx.x;
  const float* src;
  if (r < 64) {
    src = Wq + (size_t)r * kC;
    if (t == 0) ball[r] = bq[r];
  } else if (r < 128) {
    src = Wk + (size_t)(r - 64) * kC;
    if (t == 0) ball[r] = bk[r - 64];
  } else {
    src = Wv + (size_t)(r - 128) * kC;
    if (t == 0) ball[r] = bv[r - 128];
  }
#pragma unroll
  for (int p = 0; p < 2; ++p) {
    const int c = p * 256 + t;
    const float v = src[c];
    const unsigned short h = f32_to_bf16_rn(v);
    const unsigned short l = f32_to_bf16_rn(v - bf16_to_f32(h));
    wpk[(size_t)r * kC + c] = (short)h;
    wpk[(size_t)kO * kC + (size_t)r * kC + c] = (short)l;
  }
}

// ---------------- pack x: fp32 [c][l] -> bf16 hi/lo [l][c] ----------------
__global__ __launch_bounds__(256) void pack_x(
    const float* __restrict__ x, short* __restrict__ xpk,
    int b_off, size_t xstride) {
  __shared__ float sT[64][65];
  const int l0 = blockIdx.x * 64;
  const int c0 = blockIdx.y * 64;
  const int b = b_off + blockIdx.z;
  const int t = threadIdx.x;
  const float* xb = x + (size_t)b * kC * kL;
  short* xo = xpk + (size_t)blockIdx.z * xstride;
#pragma unroll
  for (int p = 0; p < 4; ++p) {
    const int ch = p * 256 + t;
    const int c = ch >> 4, l4 = (ch & 15) * 4;
    float4 v = *(const float4*)(xb + (size_t)(c0 + c) * kL + l0 + l4);
    sT[c][l4 + 0] = v.x; sT[c][l4 + 1] = v.y; sT[c][l4 + 2] = v.z; sT[c][l4 + 3] = v.w;
  }
  __syncthreads();
#pragma unroll
  for (int p = 0; p < 2; ++p) {
    const int ch = p * 256 + t;
    const int l = ch >> 3, cg = ch & 7;
    short hi[8], lo[8];
#pragma unroll
    for (int j = 0; j < 8; ++j) {
      const float v = sT[cg * 8 + j][l];
      const unsigned short h = f32_to_bf16_rn(v);
      hi[j] = (short)h;
      lo[j] = (short)f32_to_bf16_rn(v - bf16_to_f32(h));
    }
    short* dh = xo + (size_t)(l0 + l) * kC + c0 + cg * 8;
    *(bf16x8*)dh = *(bf16x8*)hi;
    *(bf16x8*)(dh + (size_t)kL * kC) = *(bf16x8*)lo;
  }
}

// ---------------- projection GEMM via bf16 MFMA, split precision ----------------
// 1D grid, XCD-aware decode: the 5 m-tiles of one (b, n-tile) run consecutively
// on the SAME XCD (B-tile L2 reuse). Epilogues LDS-transposed -> full-line stores.
__global__ __launch_bounds__(256, 2) void proj_mfma(
    const short* __restrict__ xpk, size_t xstride,
    const short* __restrict__ wpk,
    const float* __restrict__ ball, float* __restrict__ qkv,
    int b_off, int gpx) {
  __shared__ short S[34816];   // 69,632 B: main 64KB staging + epilogue transpose
  short* A_h = S;
  short* A_l = S + 8192;
  short* B_h = S + 16384;
  short* B_l = S + 24576;

  // XCD-aware decode
  const int L = blockIdx.x;
  const int xcd = L & 7;
  const int s = L >> 3;
  const int q5 = s / 5;
  const int mt = s - q5 * 5;
  const int g = xcd * gpx + q5;
  const int zz = g >> 7;               // batch index within launch
  const int b = b_off + zz;
  const int n0 = (g & 127) * 128;
  const int m0 = mt * 128;
  const bool qk = (mt == 0);

  const int t = threadIdx.x;
  const int wid = t >> 6, lane = t & 63;
  const int wr = wid >> 1, wc = wid & 1;
  const int lr = lane & 15, lg = lane >> 4;
  const int srow8 = lane >> 3;
  const int skg = (lane & 7) ^ srow8;
  const short* xo = xpk + (size_t)zz * xstride;

  f32x4 acc[4][4];
#pragma unroll
  for (int i = 0; i < 4; ++i)
#pragma unroll
    for (int j = 0; j < 4; ++j) acc[i][j] = (f32x4)(0.f);

  for (int kt = 0; kt < 8; ++kt) {
    const int k0 = kt * 64;
#pragma unroll
    for (int p = 0; p < 4; ++p) {
      const int ck = p * 4 + wid;
      const int row = ck * 8 + srow8;
      const short* srcA = wpk + (size_t)(m0 + row) * kC + k0 + skg * 8;
      const short* srcB = xo + (size_t)(n0 + row) * kC + k0 + skg * 8;
      __builtin_amdgcn_global_load_lds(
          (const __attribute__((address_space(1))) void*)srcA,
          (__attribute__((address_space(3))) void*)&A_h[ck * 512], 16, 0, 0);
      __builtin_amdgcn_global_load_lds(
          (const __attribute__((address_space(1))) void*)(srcA + (size_t)kO * kC),
          (__attribute__((address_space(3))) void*)&A_l[ck * 512], 16, 0, 0);
      __builtin_amdgcn_global_load_lds(
          (const __attribute__((address_space(1))) void*)srcB,
          (__attribute__((address_space(3))) void*)&B_h[ck * 512], 16, 0, 0);
      if (qk)
        __builtin_amdgcn_global_load_lds(
            (const __attribute__((address_space(1))) void*)(srcB + (size_t)kL * kC),
            (__attribute__((address_space(3))) void*)&B_l[ck * 512], 16, 0, 0);
    }
    __syncthreads();
#pragma unroll
    for (int ks = 0; ks < 2; ++ks) {
      bf16x8 ah[4], al[4], bh[4], bl[4];
#pragma unroll
      for (int mf = 0; mf < 4; ++mf) {
        const int row = wr * 64 + mf * 16 + lr;
        const int kg = ks * 4 + lg;
        const int off = row * 64 + ((kg ^ (row & 7)) << 3);
        ah[mf] = *(const bf16x8*)&A_h[off];
        al[mf] = *(const bf16x8*)&A_l[off];
      }
#pragma unroll
      for (int nf = 0; nf < 4; ++nf) {
        const int row = wc * 64 + nf * 16 + lr;
        const int kg = ks * 4 + lg;
        const int off = row * 64 + ((kg ^ (row & 7)) << 3);
        bh[nf] = *(const bf16x8*)&B_h[off];
        if (qk) bl[nf] = *(const bf16x8*)&B_l[off];
      }
#pragma unroll
      for (int mf = 0; mf < 4; ++mf)
#pragma unroll
        for (int nf = 0; nf < 4; ++nf) {
          acc[mf][nf] = __builtin_amdgcn_mfma_f32_16x16x32_bf16(
              ah[mf], bh[nf], acc[mf][nf], 0, 0, 0);
          acc[mf][nf] = __builtin_amdgcn_mfma_f32_16x16x32_bf16(
              al[mf], bh[nf], acc[mf][nf], 0, 0, 0);
          if (qk)
            acc[mf][nf] = __builtin_amdgcn_mfma_f32_16x16x32_bf16(
                ah[mf], bl[nf], acc[mf][nf], 0, 0, 0);
        }
    }
    __syncthreads();
  }

  if (qk) {
    // ---- stage hi/lo as [l 128][m 128] (chunk-XOR swizzled, stride 136) ----
    short* sHI = S;
    short* sLO = S + 17408;
#pragma unroll
    for (int mf = 0; mf < 4; ++mf) {
#pragma unroll
      for (int r = 0; r < 4; ++r) {
        const int m = wr * 64 + mf * 16 + lg * 4 + r;
        const float bias = ball[m];
#pragma unroll
        for (int nf = 0; nf < 4; ++nf) {
          const int lo_l = wc * 64 + nf * 16 + lr;
          const float val = acc[mf][nf][r] + bias;
          const unsigned short h = f32_to_bf16_rn(val);
          const unsigned short lo = f32_to_bf16_rn(val - bf16_to_f32(h));
          const int addr = lo_l * 136 + (((m >> 3) ^ (lo_l & 7)) << 3) + (m & 7);
          sHI[addr] = (short)h;
          sLO[addr] = (short)lo;
        }
      }
    }
    __syncthreads();
    unsigned short* qkbb = (unsigned short*)qkv + (size_t)b * kO * kL * 2;
#pragma unroll
    for (int it = 0; it < 8; ++it) {
      const int tt = it * 256 + t;          // 0..2047
      const int ch = tt & 7;
      const int plane = (tt >> 3) & 1;      // 0=q,1=k
      const int lo_l = tt >> 4;             // 0..127
      const int phys = plane * 8 + (ch ^ (lo_l & 7));
      uint4 h4 = *(const uint4*)&sHI[lo_l * 136 + phys * 8];
      uint4 l4 = *(const uint4*)&sLO[lo_l * 136 + phys * 8];
      unsigned short* qw = qkbb + (plane ? KH_OFF : QH_OFF)
          + ((size_t)(n0 + lo_l) * 64 + ch * 8);
      *(uint4*)qw = h4;
      *(uint4*)(qw + QL_OFF) = l4;
    }
  } else {
    // ---- stage [m 128][l 128] (chunk-XOR swizzled, stride 136) ----
    short* sV16 = S;
#pragma unroll
    for (int mf = 0; mf < 4; ++mf) {
#pragma unroll
      for (int r = 0; r < 4; ++r) {
        const int m = wr * 64 + mf * 16 + lg * 4 + r;
        const float bias = ball[m0 + m];
#pragma unroll
        for (int nf = 0; nf < 4; ++nf) {
          const int lo_l = wc * 64 + nf * 16 + lr;
          const int addr = m * 136 + ((((lo_l) >> 3) ^ (m & 7)) << 3) + (lo_l & 7);
          sV16[addr] = (short)f32_to_bf16_rn(acc[mf][nf][r] + bias);
        }
      }
    }
    __syncthreads();
    unsigned short* vbf =
        (unsigned short*)(qkv + ((size_t)b * kO + 128) * kL);
#pragma unroll
    for (int it = 0; it < 8; ++it) {
      const int tt = it * 256 + t;          // 0..2047 = 128m x 16 chunks
      const int ch = tt & 15;
      const int m = tt >> 4;
      const int phys = ch ^ (m & 7);
      uint4 v4 = *(const uint4*)&sV16[m * 136 + phys * 8];
      *(uint4*)(vbf + (size_t)(m0 + m - 128) * kL + n0 + ch * 8) = v4;
    }
  }
}

// ---------------- qktrans: qkb [h][w][c] -> qkbT [w][h][c] (all 4 planes) ----
__global__ __launch_bounds__(256) void qktrans_kernel(float* qkv) {
  const int h = blockIdx.x;
  const int b = blockIdx.y;
  const unsigned short* qkb = (const unsigned short*)qkv + (size_t)b * kO * kL * 2;
  unsigned short* tb =
      (unsigned short*)(qkv + ((size_t)b * kO + 128) * kL) + CTMP_OFF;
  const int t = threadIdx.x;
  const int q8 = t & 7, wbase = t >> 3;    // 32 w per pass
#pragma unroll
  for (int plane = 0; plane < 4; ++plane) {
    const unsigned short* src = qkb + (size_t)plane * 1048576;
    unsigned short* dst = tb + (size_t)plane * 1048576;
#pragma unroll
    for (int ps = 0; ps < 4; ++ps) {
      const int w = wbase + ps * 32;
      uint4 v = *(const uint4*)(src + ((size_t)h * 128 + w) * 64 + q8 * 8);
      *(uint4*)(dst + ((size_t)w * 128 + h) * 64 + q8 * 8) = v;
    }
  }
}

// ---------------- scores via MFMA, 3-pass split precision ----------------
template <int COL>
__global__ __launch_bounds__(256) void escore_mfma(
    const unsigned short* __restrict__ qh, const unsigned short* __restrict__ ql,
    const unsigned short* __restrict__ kh, const unsigned short* __restrict__ kl,
    float* __restrict__ e) {
  const int bi = blockIdx.x;
  const int b = bi >> 7, idx = bi & 127;
  const int t = threadIdx.x;
  const int wid = t >> 6, lane = t & 63;
  const int wj = wid >> 1, wh = wid & 1;
  const int lr = lane & 15, lg = lane >> 4;

  const size_t base = (size_t)b * ((size_t)kO * kL * 2) + (size_t)idx * 8192;

  f32x4 acc[4][4];
#pragma unroll
  for (int i = 0; i < 4; ++i)
#pragma unroll
    for (int j = 0; j < 4; ++j) acc[i][j] = (f32x4)(0.f);

#pragma unroll
  for (int ks = 0; ks < 2; ++ks) {
    bf16x8 ah[4], al[4], bh[4], bl[4];
#pragma unroll
    for (int mf = 0; mf < 4; ++mf) {
      const size_t ro = base + (size_t)(wj * 64 + mf * 16 + lr) * 64
          + ks * 32 + lg * 8;
      ah[mf] = *(const bf16x8*)(kh + ro);
      al[mf] = *(const bf16x8*)(kl + ro);
    }
#pragma unroll
    for (int nf = 0; nf < 4; ++nf) {
      const size_t ro = base + (size_t)(wh * 64 + nf * 16 + lr) * 64
          + ks * 32 + lg * 8;
      bh[nf] = *(const bf16x8*)(qh + ro);
      bl[nf] = *(const bf16x8*)(ql + ro);
    }
#pragma unroll
    for (int mf = 0; mf < 4; ++mf)
#pragma unroll
      for (int nf = 0; nf < 4; ++nf) {
        acc[mf][nf] = __builtin_amdgcn_mfma_f32_16x16x32_bf16(
            ah[mf], bh[nf], acc[mf][nf], 0, 0, 0);
        acc[mf][nf] = __builtin_amdgcn_mfma_f32_16x16x32_bf16(
            ah[mf], bl[nf], acc[mf][nf], 0, 0, 0);
        acc[mf][nf] = __builtin_amdgcn_mfma_f32_16x16x32_bf16(
            al[mf], bh[nf], acc[mf][nf], 0, 0, 0);
      }
  }
  const float NEG_INF = __int_as_float(0xff800000);
#pragma unroll
  for (int mf = 0; mf < 4; ++mf) {
    const int row0 = wj * 64 + mf * 16 + lg * 4;
#pragma unroll
    for (int nf = 0; nf < 4; ++nf) {
      const int cl = wh * 64 + nf * 16 + lr;
      float o[4];
#pragma unroll
      for (int r = 0; r < 4; ++r) {
        float v = acc[mf][nf][r];
        if (COL && (row0 + r == cl)) v = NEG_INF;
        o[r] = v;
      }
      float* dst;
      if (COL)
        dst = e + (((size_t)b * kH + cl) * kW + idx) * 256 + 128 + row0;
      else
        dst = e + (((size_t)b * kH + idx) * kW + cl) * 256 + row0;
      *(float4*)dst = *(const float4*)o;
    }
  }
}

// ---------------- softmax; row half -> bf16 arowT, col half -> bf16 afrag ----
__global__ __launch_bounds__(256) void softmax_kernel(
    float* __restrict__ e, float* qkv_base) {
  const int t = threadIdx.x;
  const int wv = t >> 6, lane = t & 63;
  const size_t pix = (size_t)blockIdx.x * 4 + wv;
  float* p = e + pix * 256 + lane * 4;
  float4 v = *(const float4*)p;
  float m = fmaxf(fmaxf(v.x, v.y), fmaxf(v.z, v.w));
#pragma unroll
  for (int off = 32; off > 0; off >>= 1) m = fmaxf(m, __shfl_xor(m, off, 64));
  float e0 = expf(v.x - m), e1 = expf(v.y - m), e2 = expf(v.z - m), e3 = expf(v.w - m);
  float s = e0 + e1 + e2 + e3;
#pragma unroll
  for (int off = 32; off > 0; off >>= 1) s += __shfl_xor(s, off, 64);
  const float inv = 1.0f / s;
  const float o0 = e0 * inv, o1 = e1 * inv, o2 = e2 * inv, o3 = e3 * inv;
  const int b = (int)(pix >> 14);
  const int h = (int)((pix >> 7) & 127);
  const int w = (int)(pix & 127);
  unsigned short* base = (unsigned short*)qkv_base + (size_t)b * kO * kL * 2;
  if (lane < 32) {
    unsigned short* dst = base + AROWT_OFF + (((size_t)h * kW + w) * 128 + lane * 4);
    *(uint2*)dst = make_uint2(pack_bf16x2(o0, o1), pack_bf16x2(o2, o3));
  } else {
    const int s32 = lane - 32;
    const int jb = s32 >> 3;
    const int lg = (s32 >> 1) & 3;
    const int eoff = (s32 & 1) * 4;
    const int hb = h >> 4, hr = h & 15;
    unsigned short* dst = base + (size_t)w * 16384
        + (((size_t)(jb * 8 + hb) * 64 + lg * 16 + hr) * 8 + eoff);
    *(uint2*)dst = make_uint2(pack_bf16x2(o0, o1), pack_bf16x2(o2, o3));
  }
}

// ---------------- vtrans: vbf bf16 [c][l] -> vfrag bf16 (MFMA A-frag order) ----
__global__ __launch_bounds__(256) void vtrans_kernel(
    const float* __restrict__ qkv, unsigned short* __restrict__ vfrag) {
  __shared__ float sT[16 * VT_SW];
  const int cb = blockIdx.x;
  const int wt = blockIdx.y;
  const int b  = blockIdx.z;
  const int t = threadIdx.x;
  const int lane = t & 63, wd = t >> 6;
  const int lr = lane & 15, lg = lane >> 4;
  const unsigned short* vb =
      (const unsigned short*)(qkv + ((size_t)b * kO + 128) * kL)
      + (size_t)(cb * 16) * kL + wt * 16;
  unsigned short* vfb = vfrag + (size_t)b * VFRAG_B;

  for (int half = 0; half < 2; ++half) {
    const int j0 = half * 64;
#pragma unroll
    for (int p = 0; p < 16; ++p) {
      const int g = p * 256 + t;
      const int wq = g & 3;
      const int j = (g >> 2) & 63;
      const int ci = p;
      uint2 v2 = *(const uint2*)(vb + (size_t)ci * kL + (size_t)(j0 + j) * kW + wq * 4);
      float* d = sT + ci * VT_SC + j;
      d[(wq * 4 + 0) * VT_SW] = bf16_to_f32((unsigned short)(v2.x & 0xffff));
      d[(wq * 4 + 1) * VT_SW] = bf16_to_f32((unsigned short)(v2.x >> 16));
      d[(wq * 4 + 2) * VT_SW] = bf16_to_f32((unsigned short)(v2.y & 0xffff));
      d[(wq * 4 + 3) * VT_SW] = bf16_to_f32((unsigned short)(v2.y >> 16));
    }
    __syncthreads();
#pragma unroll
    for (int wi = 0; wi < 4; ++wi) {
      const int w = wd * 4 + wi;
#pragma unroll
      for (int ktl = 0; ktl < 2; ++ktl) {
        const float* s = sT + w * VT_SW + lr * VT_SC + ktl * 32 + lg * 8;
        float a[8];
        *(float4*)(a + 0) = *(const float4*)(s + 0);
        *(float4*)(a + 4) = *(const float4*)(s + 4);
        const int ktg = half * 2 + ktl;
        unsigned short* dst = vfb
            + ((((size_t)(wt * 16 + w) * 32 + cb) * 4 + ktg) * 64 + lane) * 8;
        uint4 o = make_uint4(pack_bf16x2(a[0], a[1]), pack_bf16x2(a[2], a[3]),
                             pack_bf16x2(a[4], a[5]), pack_bf16x2(a[6], a[7]));
        *(uint4*)dst = o;
      }
    }
    __syncthreads();
  }
}

// ---------------- col aggregation: direct frag loads; writes bf16 ctmp ----------------
__global__ __launch_bounds__(1024) void colagg_mfma(
    float* qkv, const unsigned short* __restrict__ vfrag) {
  __shared__ float sO[64 * SOC];
  const int gx = blockIdx.x;
  const int ct = gx & 7, ht = gx >> 3;
  const int c0 = ct * 64, h0 = ht * 64;
  const int w0 = blockIdx.y * 16;
  const int b = blockIdx.z;
  const int t = threadIdx.x;
  const int wv = t >> 6, lane = t & 63;
  const int lr = lane & 15, lg = lane >> 4;
  const int w = w0 + wv;

  f32x4 acc[4][4];
#pragma unroll
  for (int i = 0; i < 4; ++i)
#pragma unroll
    for (int j = 0; j < 4; ++j) acc[i][j] = (f32x4)(0.f);

  const unsigned short* ab = (const unsigned short*)qkv + (size_t)b * kO * kL * 2
      + (size_t)w * 16384;
  const unsigned short* vfb = vfrag + (size_t)b * VFRAG_B
      + ((size_t)w * 32 + ct * 4) * 2048;
  unsigned short* ctmp =
      (unsigned short*)(qkv + ((size_t)b * kO + 128) * kL) + CTMP_OFF;

  for (int kt = 0; kt < 4; ++kt) {
    bf16x8 vf[4], af[4];
#pragma unroll
    for (int mf = 0; mf < 4; ++mf)
      vf[mf] = *(const bf16x8*)(vfb + ((size_t)mf * 2048 + kt * 512 + lane * 8));
#pragma unroll
    for (int nf = 0; nf < 4; ++nf)
      af[nf] = *(const bf16x8*)(
          ab + (((size_t)(kt * 8 + ht * 4 + nf) * 64 + lane) * 8));
#pragma unroll
    for (int mf = 0; mf < 4; ++mf)
#pragma unroll
      for (int nf = 0; nf < 4; ++nf)
        acc[mf][nf] = __builtin_amdgcn_mfma_f32_16x16x32_bf16(
            vf[mf], af[nf], acc[mf][nf], 0, 0, 0);
  }

  const int ew4 = t & 3, ehh = (t >> 2) & 15, ecb = t >> 6;
  for (int nf = 0; nf < 4; ++nf) {
    __syncthreads();
#pragma unroll
    for (int mf = 0; mf < 4; ++mf)
#pragma unroll
      for (int r = 0; r < 4; ++r)
        sO[(mf * 16 + lg * 4 + r) * SOC + lr * SOW + wv] = acc[mf][nf][r];
    __syncthreads();
#pragma unroll
    for (int q = 0; q < 4; ++q) {
      const int c = q * 16 + ecb;
      const float* s = &sO[c * SOC + ehh * SOW + ew4 * 4];
      unsigned u0 = pack_bf16x2(s[0], s[1]);
      unsigned u1 = pack_bf16x2(s[2], s[3]);
      unsigned short* dst = ctmp + ((size_t)(c0 + c) * kL
          + (size_t)(h0 + nf * 16 + ehh) * kW + w0 + ew4 * 4);
      *(uint2*)dst = make_uint2(u0, u1);
    }
  }
}

// ---------------- row aggregation: direct frags; LDS-transposed vector epilogue ----
__global__ __launch_bounds__(256) void rowagg_mfma(
    const float* qkv, float* __restrict__ out) {
  __shared__ float sO[64 * ROW_SW];
  const int ct = blockIdx.x;
  const int bh = blockIdx.y;
  const int b = bh >> 7, h = bh & 127;
  const int c0 = ct * 128;
  const int t = threadIdx.x;
  const int wid = t >> 6, lane = t & 63;
  const int wr = wid >> 1, wc = wid & 1;
  const int lr = lane & 15, lg = lane >> 4;

  f32x4 acc[4][4];
#pragma unroll
  for (int i = 0; i < 4; ++i)
#pragma unroll
    for (int j = 0; j < 4; ++j) acc[i][j] = (f32x4)(0.f);

  const unsigned short* vbf =
      (const unsigned short*)(qkv + ((size_t)b * kO + 128) * kL);
  const unsigned short* ctmp = vbf + CTMP_OFF;
  const unsigned short* arbase = (const unsigned short*)qkv
      + (size_t)b * kO * kL * 2 + AROWT_OFF + (size_t)h * kW * 128;

#pragma unroll
  for (int s = 0; s < 4; ++s) {
    bf16x8 vfr[4], afr[4];
#pragma unroll
    for (int mf = 0; mf < 4; ++mf) {
      const int c = c0 + wr * 64 + mf * 16 + lr;
      vfr[mf] = *(const bf16x8*)(
          vbf + (size_t)c * kL + (size_t)h * kW + s * 32 + lg * 8);
    }
#pragma unroll
    for (int nf = 0; nf < 4; ++nf) {
      const int w = wc * 64 + nf * 16 + lr;
      afr[nf] = *(const bf16x8*)(arbase + (size_t)w * 128 + s * 32 + lg * 8);
    }
#pragma unroll
    for (int mf = 0; mf < 4; ++mf)
#pragma unroll
      for (int nf = 0; nf < 4; ++nf)
        acc[mf][nf] = __builtin_amdgcn_mfma_f32_16x16x32_bf16(
            vfr[mf], afr[nf], acc[mf][nf], 0, 0, 0);
  }

  const int wq = t & 31;
  const int cc8 = t >> 5;
  const unsigned short* ctb = ctmp + (size_t)h * kW;
  float* outb = out + ((size_t)b * kC * kL + (size_t)h * kW);
  for (int half = 0; half < 2; ++half) {
    if (wr == half) {
#pragma unroll
      for (int mf = 0; mf < 4; ++mf)
#pragma unroll
        for (int nf = 0; nf < 4; ++nf)
#pragma unroll
          for (int r = 0; r < 4; ++r)
            sO[(mf * 16 + lg * 4 + r) * ROW_SW + wc * 64 + nf * 16 + lr] =
                acc[mf][nf][r];
    }
    __syncthreads();
#pragma unroll
    for (int i = 0; i < 8; ++i) {
      const int cl = i * 8 + cc8;
      const size_t c = c0 + half * 64 + cl;
      float4 v = *(const float4*)&sO[cl * ROW_SW + wq * 4];
      uint2 c2 = *(const uint2*)(ctb + c * kL + wq * 4);
      v.x += bf16_to_f32((unsigned short)(c2.x & 0xffff));
      v.y += bf16_to_f32((unsigned short)(c2.x >> 16));
      v.z += bf16_to_f32((unsigned short)(c2.y & 0xffff));
      v.w += bf16_to_f32((unsigned short)(c2.y >> 16));
      *(float4*)(outb + c * kL + wq * 4) = v;
    }
    __syncthreads();
  }
}

extern "C" void kernel_launch(void* const* d_in, const int* in_sizes, int n_in,
                              void* d_out, int out_size, void* d_ws, size_t ws_size,
                              hipStream_t stream) {
  (void)in_sizes; (void)n_in; (void)out_size;
  const float* x  = (const float*)d_in[0];
  const float* Wq = (const float*)d_in[1];
  const float* bq = (const float*)d_in[2];
  const float* Wk = (const float*)d_in[3];
  const float* bk = (const float*)d_in[4];
  const float* Wv = (const float*)d_in[5];
  const float* bv = (const float*)d_in[6];
  float* out = (float*)d_out;
  float* ws  = (float*)d_ws;

  short* wpk = (short*)(ws + OFF_WALL);
  float* ball = ws + OFF_BALL;
  float* qkv  = ws + OFF_QKV;
  float* e    = ws + OFF_E;
  unsigned short* vfrag = (unsigned short*)(ws + OFF_E);

  pack_w<<<dim3(kO), dim3(256), 0, stream>>>(Wq, bq, Wk, bk, Wv, bv, wpk, ball);

  const size_t xpk_batch = (size_t)2 * kL * kC;
  const size_t need = WS_FLOATS * sizeof(float)
      + (size_t)kB * xpk_batch * sizeof(short);
  if (ws_size >= need) {
    short* xall = (short*)(ws + WS_FLOATS);
    pack_x<<<dim3(kL / 64, kC / 64, kB), dim3(256), 0, stream>>>(
        x, xall, 0, xpk_batch);
    proj_mfma<<<dim3(2560), dim3(256), 0, stream>>>(
        xall, xpk_batch, wpk, ball, qkv, 0, 64);
  } else {
    short* xpk = (short*)(ws + OFF_E);
    for (int b = 0; b < kB; ++b) {
      pack_x<<<dim3(kL / 64, kC / 64, 1), dim3(256), 0, stream>>>(x, xpk, b, 0);
      proj_mfma<<<dim3(640), dim3(256), 0, stream>>>(
          xpk, 0, wpk, ball, qkv, b, 16);
    }
  }

  qktrans_kernel<<<dim3(kH, kB), dim3(256), 0, stream>>>(qkv);

  unsigned short* qkb0 = (unsigned short*)qkv;
  escore_mfma<0><<<dim3(kB * kH), dim3(256), 0, stream>>>(
      qkb0 + QH_OFF, qkb0 + QL_OFF, qkb0 + KH_OFF, qkb0 + KL_OFF, e);
  unsigned short* vt0 = (unsigned short*)qkv + (size_t)128 * kL * 2 + CTMP_OFF;
  escore_mfma<1><<<dim3(kB * kW), dim3(256), 0, stream>>>(
      vt0 + 0, vt0 + 1048576, vt0 + 2097152, vt0 + 3145728, e);
  softmax_kernel<<<dim3(kB * kH * kW / 4), dim3(256), 0, stream>>>(e, qkv);
  vtrans_kernel<<<dim3(32, 8, kB), dim3(256), 0, stream>>>(qkv, vfrag);
  colagg_mfma<<<dim3(16, kW / 16, kB), dim3(1024), 0, stream>>>(qkv, vfrag);
  rowagg_mfma<<<dim3(4, kB * kH), dim3(256), 0, stream>>>(qkv, out);
}

// Round 16
// 381.474 us; speedup vs baseline: 1.2963x; 1.0329x over previous
//
#include <hip/hip_runtime.h>
#include <hip/hip_bf16.h>

namespace {
constexpr int kB = 4;
constexpr int kC = 512;
constexpr int kH = 128;
constexpr int kW = 128;
constexpr int kL = kH * kW;   // 16384
constexpr int kO = 640;

// workspace layout (float offsets)
constexpr size_t OFF_WALL = 0;
constexpr size_t OFF_BALL = (size_t)kO * kC;
constexpr size_t OFF_QKV  = OFF_BALL + kO;
constexpr size_t OFF_E    = OFF_QKV + (size_t)kB * kO * kL;
constexpr size_t WS_FLOATS = OFF_E + (size_t)kB * kH * kW * 256;
// q/k region per batch (8.4MB): qkb planes qh@0 ql@1M kh@2M kl@3M (u16),
//   later overwritten by softmax: afrag[0,2M) + arowT[2M,4M)
// v region per batch (33.5MB): vbf[c][l] bf16 [0,8.4M); [8.4M,16.8M) holds
//   qkbT planes (qktrans -> escore_col), then ctmp (colagg -> rowagg)
// e region (67MB): xpk-fallback -> scores fp32 -> vfrag bf16

typedef __attribute__((ext_vector_type(8))) short bf16x8;
typedef __attribute__((ext_vector_type(4))) float f32x4;

__device__ __forceinline__ unsigned short f32_to_bf16_rn(float f) {
  unsigned u = __float_as_uint(f);
  unsigned r = (u + 0x7FFFu + ((u >> 16) & 1u)) >> 16;
  return (unsigned short)r;
}
__device__ __forceinline__ float bf16_to_f32(unsigned short h) {
  return __uint_as_float(((unsigned)h) << 16);
}
__device__ __forceinline__ unsigned pack_bf16x2(float a, float b) {
  return (unsigned)f32_to_bf16_rn(a) | ((unsigned)f32_to_bf16_rn(b) << 16);
}
constexpr int SOW = 17;
constexpr int SOC = 16 * SOW + 1;   // 273
constexpr int ROW_SW = 132;
constexpr size_t AROWT_OFF = 2097152;
constexpr size_t QH_OFF = 0;
constexpr size_t QL_OFF = 1048576;
constexpr size_t KH_OFF = 2097152;
constexpr size_t KL_OFF = 3145728;
constexpr size_t CTMP_OFF = 8388608;
constexpr int VT_SC = 68;
constexpr int VT_SW = 16 * VT_SC + 4;
constexpr size_t VFRAG_B = (size_t)kW * 32 * 4 * 64 * 8;
}

// ---------------- pack W/bias into bf16 hi/lo planes [640][512] ----------------
__global__ __launch_bounds__(256) void pack_w(
    const float* __restrict__ Wq, const float* __restrict__ bq,
    const float* __restrict__ Wk, const float* __restrict__ bk,
    const float* __restrict__ Wv, const float* __restrict__ bv,
    short* __restrict__ wpk, float* __restrict__ ball) {
  const int r = blockIdx.x;
  const int t = threadIdx.x;
  const float* src;
  if (r < 64) {
    src = Wq + (size_t)r * kC;
    if (t == 0) ball[r] = bq[r];
  } else if (r < 128) {
    src = Wk + (size_t)(r - 64) * kC;
    if (t == 0) ball[r] = bk[r - 64];
  } else {
    src = Wv + (size_t)(r - 128) * kC;
    if (t == 0) ball[r] = bv[r - 128];
  }
#pragma unroll
  for (int p = 0; p < 2; ++p) {
    const int c = p * 256 + t;
    const float v = src[c];
    const unsigned short h = f32_to_bf16_rn(v);
    const unsigned short l = f32_to_bf16_rn(v - bf16_to_f32(h));
    wpk[(size_t)r * kC + c] = (short)h;
    wpk[(size_t)kO * kC + (size_t)r * kC + c] = (short)l;
  }
}

// ---------------- pack x: fp32 [c][l] -> bf16 hi/lo [l][c] ----------------
__global__ __launch_bounds__(256) void pack_x(
    const float* __restrict__ x, short* __restrict__ xpk,
    int b_off, size_t xstride) {
  __shared__ float sT[64][65];
  const int l0 = blockIdx.x * 64;
  const int c0 = blockIdx.y * 64;
  const int b = b_off + blockIdx.z;
  const int t = threadIdx.x;
  const float* xb = x + (size_t)b * kC * kL;
  short* xo = xpk + (size_t)blockIdx.z * xstride;
#pragma unroll
  for (int p = 0; p < 4; ++p) {
    const int ch = p * 256 + t;
    const int c = ch >> 4, l4 = (ch & 15) * 4;
    float4 v = *(const float4*)(xb + (size_t)(c0 + c) * kL + l0 + l4);
    sT[c][l4 + 0] = v.x; sT[c][l4 + 1] = v.y; sT[c][l4 + 2] = v.z; sT[c][l4 + 3] = v.w;
  }
  __syncthreads();
#pragma unroll
  for (int p = 0; p < 2; ++p) {
    const int ch = p * 256 + t;
    const int l = ch >> 3, cg = ch & 7;
    short hi[8], lo[8];
#pragma unroll
    for (int j = 0; j < 8; ++j) {
      const float v = sT[cg * 8 + j][l];
      const unsigned short h = f32_to_bf16_rn(v);
      hi[j] = (short)h;
      lo[j] = (short)f32_to_bf16_rn(v - bf16_to_f32(h));
    }
    short* dh = xo + (size_t)(l0 + l) * kC + c0 + cg * 8;
    *(bf16x8*)dh = *(bf16x8*)hi;
    *(bf16x8*)(dh + (size_t)kL * kC) = *(bf16x8*)lo;
  }
}

// ---------------- proj (qk tile only): 3-pass, writes qkb hi/lo planes ----------------
__global__ __launch_bounds__(256, 2) void proj_qk_mfma(
    const short* __restrict__ xpk, size_t xstride,
    const short* __restrict__ wpk,
    const float* __restrict__ ball, float* __restrict__ qkv,
    int b_off, int gpx) {
  __shared__ short S[34816];   // 69,632 B
  short* A_h = S;
  short* A_l = S + 8192;
  short* B_h = S + 16384;
  short* B_l = S + 24576;

  const int L = blockIdx.x;
  const int xcd = L & 7;
  const int g = xcd * gpx + (L >> 3);
  const int zz = g >> 7;
  const int b = b_off + zz;
  const int n0 = (g & 127) * 128;

  const int t = threadIdx.x;
  const int wid = t >> 6, lane = t & 63;
  const int wr = wid >> 1, wc = wid & 1;
  const int lr = lane & 15, lg = lane >> 4;
  const int srow8 = lane >> 3;
  const int skg = (lane & 7) ^ srow8;
  const short* xo = xpk + (size_t)zz * xstride;

  f32x4 acc[4][4];
#pragma unroll
  for (int i = 0; i < 4; ++i)
#pragma unroll
    for (int j = 0; j < 4; ++j) acc[i][j] = (f32x4)(0.f);

  for (int kt = 0; kt < 8; ++kt) {
    const int k0 = kt * 64;
#pragma unroll
    for (int p = 0; p < 4; ++p) {
      const int ck = p * 4 + wid;
      const int row = ck * 8 + srow8;
      const short* srcA = wpk + (size_t)row * kC + k0 + skg * 8;
      const short* srcB = xo + (size_t)(n0 + row) * kC + k0 + skg * 8;
      __builtin_amdgcn_global_load_lds(
          (const __attribute__((address_space(1))) void*)srcA,
          (__attribute__((address_space(3))) void*)&A_h[ck * 512], 16, 0, 0);
      __builtin_amdgcn_global_load_lds(
          (const __attribute__((address_space(1))) void*)(srcA + (size_t)kO * kC),
          (__attribute__((address_space(3))) void*)&A_l[ck * 512], 16, 0, 0);
      __builtin_amdgcn_global_load_lds(
          (const __attribute__((address_space(1))) void*)srcB,
          (__attribute__((address_space(3))) void*)&B_h[ck * 512], 16, 0, 0);
      __builtin_amdgcn_global_load_lds(
          (const __attribute__((address_space(1))) void*)(srcB + (size_t)kL * kC),
          (__attribute__((address_space(3))) void*)&B_l[ck * 512], 16, 0, 0);
    }
    __syncthreads();
#pragma unroll
    for (int ks = 0; ks < 2; ++ks) {
      bf16x8 ah[4], al[4], bh[4], bl[4];
#pragma unroll
      for (int mf = 0; mf < 4; ++mf) {
        const int row = wr * 64 + mf * 16 + lr;
        const int kg = ks * 4 + lg;
        const int off = row * 64 + ((kg ^ (row & 7)) << 3);
        ah[mf] = *(const bf16x8*)&A_h[off];
        al[mf] = *(const bf16x8*)&A_l[off];
      }
#pragma unroll
      for (int nf = 0; nf < 4; ++nf) {
        const int row = wc * 64 + nf * 16 + lr;
        const int kg = ks * 4 + lg;
        const int off = row * 64 + ((kg ^ (row & 7)) << 3);
        bh[nf] = *(const bf16x8*)&B_h[off];
        bl[nf] = *(const bf16x8*)&B_l[off];
      }
#pragma unroll
      for (int mf = 0; mf < 4; ++mf)
#pragma unroll
        for (int nf = 0; nf < 4; ++nf) {
          acc[mf][nf] = __builtin_amdgcn_mfma_f32_16x16x32_bf16(
              ah[mf], bh[nf], acc[mf][nf], 0, 0, 0);
          acc[mf][nf] = __builtin_amdgcn_mfma_f32_16x16x32_bf16(
              al[mf], bh[nf], acc[mf][nf], 0, 0, 0);
          acc[mf][nf] = __builtin_amdgcn_mfma_f32_16x16x32_bf16(
              ah[mf], bl[nf], acc[mf][nf], 0, 0, 0);
        }
    }
    __syncthreads();
  }

  // ---- epilogue: stage hi/lo [l 128][m 128] (stride 136), uint2 r-vectorized ----
  short* sHI = S;
  short* sLO = S + 17408;
#pragma unroll
  for (int mf = 0; mf < 4; ++mf) {
    const int mbase = wr * 64 + mf * 16 + lg * 4;
    float b0 = ball[mbase + 0], b1 = ball[mbase + 1];
    float b2 = ball[mbase + 2], b3 = ball[mbase + 3];
#pragma unroll
    for (int nf = 0; nf < 4; ++nf) {
      const int lo_l = wc * 64 + nf * 16 + lr;
      float v0 = acc[mf][nf][0] + b0, v1 = acc[mf][nf][1] + b1;
      float v2 = acc[mf][nf][2] + b2, v3 = acc[mf][nf][3] + b3;
      unsigned short h4[4], l4v[4];
      h4[0] = f32_to_bf16_rn(v0); l4v[0] = f32_to_bf16_rn(v0 - bf16_to_f32(h4[0]));
      h4[1] = f32_to_bf16_rn(v1); l4v[1] = f32_to_bf16_rn(v1 - bf16_to_f32(h4[1]));
      h4[2] = f32_to_bf16_rn(v2); l4v[2] = f32_to_bf16_rn(v2 - bf16_to_f32(h4[2]));
      h4[3] = f32_to_bf16_rn(v3); l4v[3] = f32_to_bf16_rn(v3 - bf16_to_f32(h4[3]));
      const int addr = lo_l * 136 + (((mbase >> 3) ^ (lo_l & 7)) << 3) + (mbase & 7);
      *(uint2*)&sHI[addr] = *(uint2*)h4;
      *(uint2*)&sLO[addr] = *(uint2*)l4v;
    }
  }
  __syncthreads();
  unsigned short* qkbb = (unsigned short*)qkv + (size_t)b * kO * kL * 2;
#pragma unroll
  for (int it = 0; it < 8; ++it) {
    const int tt = it * 256 + t;          // 0..2047
    const int ch = tt & 7;
    const int plane = (tt >> 3) & 1;      // 0=q,1=k
    const int lo_l = tt >> 4;             // 0..127
    const int phys = plane * 8 + (ch ^ (lo_l & 7));
    uint4 h4 = *(const uint4*)&sHI[lo_l * 136 + phys * 8];
    uint4 l4 = *(const uint4*)&sLO[lo_l * 136 + phys * 8];
    unsigned short* qw = qkbb + (plane ? KH_OFF : QH_OFF)
        + ((size_t)(n0 + lo_l) * 64 + ch * 8);
    *(uint4*)qw = h4;
    *(uint4*)(qw + QL_OFF) = l4;
  }
}

// ---------------- proj (v tiles): 2-pass, 48KB LDS -> 3 blocks/CU ----------------
__global__ __launch_bounds__(256, 3) void proj_v_mfma(
    const short* __restrict__ xpk, size_t xstride,
    const short* __restrict__ wpk,
    const float* __restrict__ ball, float* __restrict__ qkv,
    int b_off, int gpx) {
  __shared__ short S[24576];   // 49,152 B
  short* A_h = S;
  short* A_l = S + 8192;
  short* B_h = S + 16384;

  const int L = blockIdx.x;
  const int xcd = L & 7;
  const int s = L >> 3;
  const int q4 = s >> 2;
  const int mt = 1 + (s & 3);           // m-tiles of one (b,n0) contiguous per XCD
  const int g = xcd * gpx + q4;
  const int zz = g >> 7;
  const int b = b_off + zz;
  const int n0 = (g & 127) * 128;
  const int m0 = mt * 128;

  const int t = threadIdx.x;
  const int wid = t >> 6, lane = t & 63;
  const int wr = wid >> 1, wc = wid & 1;
  const int lr = lane & 15, lg = lane >> 4;
  const int srow8 = lane >> 3;
  const int skg = (lane & 7) ^ srow8;
  const short* xo = xpk + (size_t)zz * xstride;

  f32x4 acc[4][4];
#pragma unroll
  for (int i = 0; i < 4; ++i)
#pragma unroll
    for (int j = 0; j < 4; ++j) acc[i][j] = (f32x4)(0.f);

  for (int kt = 0; kt < 8; ++kt) {
    const int k0 = kt * 64;
#pragma unroll
    for (int p = 0; p < 4; ++p) {
      const int ck = p * 4 + wid;
      const int row = ck * 8 + srow8;
      const short* srcA = wpk + (size_t)(m0 + row) * kC + k0 + skg * 8;
      const short* srcB = xo + (size_t)(n0 + row) * kC + k0 + skg * 8;
      __builtin_amdgcn_global_load_lds(
          (const __attribute__((address_space(1))) void*)srcA,
          (__attribute__((address_space(3))) void*)&A_h[ck * 512], 16, 0, 0);
      __builtin_amdgcn_global_load_lds(
          (const __attribute__((address_space(1))) void*)(srcA + (size_t)kO * kC),
          (__attribute__((address_space(3))) void*)&A_l[ck * 512], 16, 0, 0);
      __builtin_amdgcn_global_load_lds(
          (const __attribute__((address_space(1))) void*)srcB,
          (__attribute__((address_space(3))) void*)&B_h[ck * 512], 16, 0, 0);
    }
    __syncthreads();
#pragma unroll
    for (int ks = 0; ks < 2; ++ks) {
      bf16x8 ah[4], al[4], bh[4];
#pragma unroll
      for (int mf = 0; mf < 4; ++mf) {
        const int row = wr * 64 + mf * 16 + lr;
        const int kg = ks * 4 + lg;
        const int off = row * 64 + ((kg ^ (row & 7)) << 3);
        ah[mf] = *(const bf16x8*)&A_h[off];
        al[mf] = *(const bf16x8*)&A_l[off];
      }
#pragma unroll
      for (int nf = 0; nf < 4; ++nf) {
        const int row = wc * 64 + nf * 16 + lr;
        const int kg = ks * 4 + lg;
        const int off = row * 64 + ((kg ^ (row & 7)) << 3);
        bh[nf] = *(const bf16x8*)&B_h[off];
      }
#pragma unroll
      for (int mf = 0; mf < 4; ++mf)
#pragma unroll
        for (int nf = 0; nf < 4; ++nf) {
          acc[mf][nf] = __builtin_amdgcn_mfma_f32_16x16x32_bf16(
              ah[mf], bh[nf], acc[mf][nf], 0, 0, 0);
          acc[mf][nf] = __builtin_amdgcn_mfma_f32_16x16x32_bf16(
              al[mf], bh[nf], acc[mf][nf], 0, 0, 0);
        }
    }
    __syncthreads();
  }

  // ---- epilogue: stage [m 128][l 128] (stride 136, chunk-XOR), uint4 stores ----
  short* sV16 = S;   // 17,408 shorts <= 24,576
#pragma unroll
  for (int mf = 0; mf < 4; ++mf) {
#pragma unroll
    for (int r = 0; r < 4; ++r) {
      const int m = wr * 64 + mf * 16 + lg * 4 + r;
      const float bias = ball[m0 + m];
#pragma unroll
      for (int nf = 0; nf < 4; ++nf) {
        const int lo_l = wc * 64 + nf * 16 + lr;
        const int addr = m * 136 + ((((lo_l) >> 3) ^ (m & 7)) << 3) + (lo_l & 7);
        sV16[addr] = (short)f32_to_bf16_rn(acc[mf][nf][r] + bias);
      }
    }
  }
  __syncthreads();
  unsigned short* vbf =
      (unsigned short*)(qkv + ((size_t)b * kO + 128) * kL);
#pragma unroll
  for (int it = 0; it < 8; ++it) {
    const int tt = it * 256 + t;          // 0..2047 = 128m x 16 chunks
    const int ch = tt & 15;
    const int m = tt >> 4;
    const int phys = ch ^ (m & 7);
    uint4 v4 = *(const uint4*)&sV16[m * 136 + phys * 8];
    *(uint4*)(vbf + (size_t)(m0 + m - 128) * kL + n0 + ch * 8) = v4;
  }
}

// ---------------- qktrans: qkb [h][w][c] -> qkbT [w][h][c] (all 4 planes) ----
__global__ __launch_bounds__(256) void qktrans_kernel(float* qkv) {
  const int h = blockIdx.x;
  const int b = blockIdx.y;
  const unsigned short* qkb = (const unsigned short*)qkv + (size_t)b * kO * kL * 2;
  unsigned short* tb =
      (unsigned short*)(qkv + ((size_t)b * kO + 128) * kL) + CTMP_OFF;
  const int t = threadIdx.x;
  const int q8 = t & 7, wbase = t >> 3;    // 32 w per pass
#pragma unroll
  for (int plane = 0; plane < 4; ++plane) {
    const unsigned short* src = qkb + (size_t)plane * 1048576;
    unsigned short* dst = tb + (size_t)plane * 1048576;
#pragma unroll
    for (int ps = 0; ps < 4; ++ps) {
      const int w = wbase + ps * 32;
      uint4 v = *(const uint4*)(src + ((size_t)h * 128 + w) * 64 + q8 * 8);
      *(uint4*)(dst + ((size_t)w * 128 + h) * 64 + q8 * 8) = v;
    }
  }
}

// ---------------- scores via MFMA, 3-pass split precision ----------------
template <int COL>
__global__ __launch_bounds__(256) void escore_mfma(
    const unsigned short* __restrict__ qh, const unsigned short* __restrict__ ql,
    const unsigned short* __restrict__ kh, const unsigned short* __restrict__ kl,
    float* __restrict__ e) {
  const int bi = blockIdx.x;
  const int b = bi >> 7, idx = bi & 127;
  const int t = threadIdx.x;
  const int wid = t >> 6, lane = t & 63;
  const int wj = wid >> 1, wh = wid & 1;
  const int lr = lane & 15, lg = lane >> 4;

  const size_t base = (size_t)b * ((size_t)kO * kL * 2) + (size_t)idx * 8192;

  f32x4 acc[4][4];
#pragma unroll
  for (int i = 0; i < 4; ++i)
#pragma unroll
    for (int j = 0; j < 4; ++j) acc[i][j] = (f32x4)(0.f);

#pragma unroll
  for (int ks = 0; ks < 2; ++ks) {
    bf16x8 ah[4], al[4], bh[4], bl[4];
#pragma unroll
    for (int mf = 0; mf < 4; ++mf) {
      const size_t ro = base + (size_t)(wj * 64 + mf * 16 + lr) * 64
          + ks * 32 + lg * 8;
      ah[mf] = *(const bf16x8*)(kh + ro);
      al[mf] = *(const bf16x8*)(kl + ro);
    }
#pragma unroll
    for (int nf = 0; nf < 4; ++nf) {
      const size_t ro = base + (size_t)(wh * 64 + nf * 16 + lr) * 64
          + ks * 32 + lg * 8;
      bh[nf] = *(const bf16x8*)(qh + ro);
      bl[nf] = *(const bf16x8*)(ql + ro);
    }
#pragma unroll
    for (int mf = 0; mf < 4; ++mf)
#pragma unroll
      for (int nf = 0; nf < 4; ++nf) {
        acc[mf][nf] = __builtin_amdgcn_mfma_f32_16x16x32_bf16(
            ah[mf], bh[nf], acc[mf][nf], 0, 0, 0);
        acc[mf][nf] = __builtin_amdgcn_mfma_f32_16x16x32_bf16(
            ah[mf], bl[nf], acc[mf][nf], 0, 0, 0);
        acc[mf][nf] = __builtin_amdgcn_mfma_f32_16x16x32_bf16(
            al[mf], bh[nf], acc[mf][nf], 0, 0, 0);
      }
  }
  const float NEG_INF = __int_as_float(0xff800000);
#pragma unroll
  for (int mf = 0; mf < 4; ++mf) {
    const int row0 = wj * 64 + mf * 16 + lg * 4;
#pragma unroll
    for (int nf = 0; nf < 4; ++nf) {
      const int cl = wh * 64 + nf * 16 + lr;
      float o[4];
#pragma unroll
      for (int r = 0; r < 4; ++r) {
        float v = acc[mf][nf][r];
        if (COL && (row0 + r == cl)) v = NEG_INF;
        o[r] = v;
      }
      float* dst;
      if (COL)
        dst = e + (((size_t)b * kH + cl) * kW + idx) * 256 + 128 + row0;
      else
        dst = e + (((size_t)b * kH + idx) * kW + cl) * 256 + row0;
      *(float4*)dst = *(const float4*)o;
    }
  }
}

// ---------------- softmax; row half -> bf16 arowT, col half -> bf16 afrag ----
__global__ __launch_bounds__(256) void softmax_kernel(
    float* __restrict__ e, float* qkv_base) {
  const int t = threadIdx.x;
  const int wv = t >> 6, lane = t & 63;
  const size_t pix = (size_t)blockIdx.x * 4 + wv;
  float* p = e + pix * 256 + lane * 4;
  float4 v = *(const float4*)p;
  float m = fmaxf(fmaxf(v.x, v.y), fmaxf(v.z, v.w));
#pragma unroll
  for (int off = 32; off > 0; off >>= 1) m = fmaxf(m, __shfl_xor(m, off, 64));
  float e0 = expf(v.x - m), e1 = expf(v.y - m), e2 = expf(v.z - m), e3 = expf(v.w - m);
  float s = e0 + e1 + e2 + e3;
#pragma unroll
  for (int off = 32; off > 0; off >>= 1) s += __shfl_xor(s, off, 64);
  const float inv = 1.0f / s;
  const float o0 = e0 * inv, o1 = e1 * inv, o2 = e2 * inv, o3 = e3 * inv;
  const int b = (int)(pix >> 14);
  const int h = (int)((pix >> 7) & 127);
  const int w = (int)(pix & 127);
  unsigned short* base = (unsigned short*)qkv_base + (size_t)b * kO * kL * 2;
  if (lane < 32) {
    unsigned short* dst = base + AROWT_OFF + (((size_t)h * kW + w) * 128 + lane * 4);
    *(uint2*)dst = make_uint2(pack_bf16x2(o0, o1), pack_bf16x2(o2, o3));
  } else {
    const int s32 = lane - 32;
    const int jb = s32 >> 3;
    const int lg = (s32 >> 1) & 3;
    const int eoff = (s32 & 1) * 4;
    const int hb = h >> 4, hr = h & 15;
    unsigned short* dst = base + (size_t)w * 16384
        + (((size_t)(jb * 8 + hb) * 64 + lg * 16 + hr) * 8 + eoff);
    *(uint2*)dst = make_uint2(pack_bf16x2(o0, o1), pack_bf16x2(o2, o3));
  }
}

// ---------------- vtrans: vbf bf16 [c][l] -> vfrag bf16 (MFMA A-frag order) ----
__global__ __launch_bounds__(256) void vtrans_kernel(
    const float* __restrict__ qkv, unsigned short* __restrict__ vfrag) {
  __shared__ float sT[16 * VT_SW];
  const int cb = blockIdx.x;
  const int wt = blockIdx.y;
  const int b  = blockIdx.z;
  const int t = threadIdx.x;
  const int lane = t & 63, wd = t >> 6;
  const int lr = lane & 15, lg = lane >> 4;
  const unsigned short* vb =
      (const unsigned short*)(qkv + ((size_t)b * kO + 128) * kL)
      + (size_t)(cb * 16) * kL + wt * 16;
  unsigned short* vfb = vfrag + (size_t)b * VFRAG_B;

  for (int half = 0; half < 2; ++half) {
    const int j0 = half * 64;
#pragma unroll
    for (int p = 0; p < 16; ++p) {
      const int g = p * 256 + t;
      const int wq = g & 3;
      const int j = (g >> 2) & 63;
      const int ci = p;
      uint2 v2 = *(const uint2*)(vb + (size_t)ci * kL + (size_t)(j0 + j) * kW + wq * 4);
      float* d = sT + ci * VT_SC + j;
      d[(wq * 4 + 0) * VT_SW] = bf16_to_f32((unsigned short)(v2.x & 0xffff));
      d[(wq * 4 + 1) * VT_SW] = bf16_to_f32((unsigned short)(v2.x >> 16));
      d[(wq * 4 + 2) * VT_SW] = bf16_to_f32((unsigned short)(v2.y & 0xffff));
      d[(wq * 4 + 3) * VT_SW] = bf16_to_f32((unsigned short)(v2.y >> 16));
    }
    __syncthreads();
#pragma unroll
    for (int wi = 0; wi < 4; ++wi) {
      const int w = wd * 4 + wi;
#pragma unroll
      for (int ktl = 0; ktl < 2; ++ktl) {
        const float* s = sT + w * VT_SW + lr * VT_SC + ktl * 32 + lg * 8;
        float a[8];
        *(float4*)(a + 0) = *(const float4*)(s + 0);
        *(float4*)(a + 4) = *(const float4*)(s + 4);
        const int ktg = half * 2 + ktl;
        unsigned short* dst = vfb
            + ((((size_t)(wt * 16 + w) * 32 + cb) * 4 + ktg) * 64 + lane) * 8;
        uint4 o = make_uint4(pack_bf16x2(a[0], a[1]), pack_bf16x2(a[2], a[3]),
                             pack_bf16x2(a[4], a[5]), pack_bf16x2(a[6], a[7]));
        *(uint4*)dst = o;
      }
    }
    __syncthreads();
  }
}

// ---------------- col aggregation: direct frag loads; writes bf16 ctmp ----------------
__global__ __launch_bounds__(1024) void colagg_mfma(
    float* qkv, const unsigned short* __restrict__ vfrag) {
  __shared__ float sO[64 * SOC];
  const int gx = blockIdx.x;
  const int ct = gx & 7, ht = gx >> 3;
  const int c0 = ct * 64, h0 = ht * 64;
  const int w0 = blockIdx.y * 16;
  const int b = blockIdx.z;
  const int t = threadIdx.x;
  const int wv = t >> 6, lane = t & 63;
  const int lr = lane & 15, lg = lane >> 4;
  const int w = w0 + wv;

  f32x4 acc[4][4];
#pragma unroll
  for (int i = 0; i < 4; ++i)
#pragma unroll
    for (int j = 0; j < 4; ++j) acc[i][j] = (f32x4)(0.f);

  const unsigned short* ab = (const unsigned short*)qkv + (size_t)b * kO * kL * 2
      + (size_t)w * 16384;
  const unsigned short* vfb = vfrag + (size_t)b * VFRAG_B
      + ((size_t)w * 32 + ct * 4) * 2048;
  unsigned short* ctmp =
      (unsigned short*)(qkv + ((size_t)b * kO + 128) * kL) + CTMP_OFF;

  for (int kt = 0; kt < 4; ++kt) {
    bf16x8 vf[4], af[4];
#pragma unroll
    for (int mf = 0; mf < 4; ++mf)
      vf[mf] = *(const bf16x8*)(vfb + ((size_t)mf * 2048 + kt * 512 + lane * 8));
#pragma unroll
    for (int nf = 0; nf < 4; ++nf)
      af[nf] = *(const bf16x8*)(
          ab + (((size_t)(kt * 8 + ht * 4 + nf) * 64 + lane) * 8));
#pragma unroll
    for (int mf = 0; mf < 4; ++mf)
#pragma unroll
      for (int nf = 0; nf < 4; ++nf)
        acc[mf][nf] = __builtin_amdgcn_mfma_f32_16x16x32_bf16(
            vf[mf], af[nf], acc[mf][nf], 0, 0, 0);
  }

  const int ew4 = t & 3, ehh = (t >> 2) & 15, ecb = t >> 6;
  for (int nf = 0; nf < 4; ++nf) {
    __syncthreads();
#pragma unroll
    for (int mf = 0; mf < 4; ++mf)
#pragma unroll
      for (int r = 0; r < 4; ++r)
        sO[(mf * 16 + lg * 4 + r) * SOC + lr * SOW + wv] = acc[mf][nf][r];
    __syncthreads();
#pragma unroll
    for (int q = 0; q < 4; ++q) {
      const int c = q * 16 + ecb;
      const float* s = &sO[c * SOC + ehh * SOW + ew4 * 4];
      unsigned u0 = pack_bf16x2(s[0], s[1]);
      unsigned u1 = pack_bf16x2(s[2], s[3]);
      unsigned short* dst = ctmp + ((size_t)(c0 + c) * kL
          + (size_t)(h0 + nf * 16 + ehh) * kW + w0 + ew4 * 4);
      *(uint2*)dst = make_uint2(u0, u1);
    }
  }
}

// ---------------- row aggregation: direct frags; LDS-transposed vector epilogue ----
__global__ __launch_bounds__(256) void rowagg_mfma(
    const float* qkv, float* __restrict__ out) {
  __shared__ float sO[64 * ROW_SW];
  const int ct = blockIdx.x;
  const int bh = blockIdx.y;
  const int b = bh >> 7, h = bh & 127;
  const int c0 = ct * 128;
  const int t = threadIdx.x;
  const int wid = t >> 6, lane = t & 63;
  const int wr = wid >> 1, wc = wid & 1;
  const int lr = lane & 15, lg = lane >> 4;

  f32x4 acc[4][4];
#pragma unroll
  for (int i = 0; i < 4; ++i)
#pragma unroll
    for (int j = 0; j < 4; ++j) acc[i][j] = (f32x4)(0.f);

  const unsigned short* vbf =
      (const unsigned short*)(qkv + ((size_t)b * kO + 128) * kL);
  const unsigned short* ctmp = vbf + CTMP_OFF;
  const unsigned short* arbase = (const unsigned short*)qkv
      + (size_t)b * kO * kL * 2 + AROWT_OFF + (size_t)h * kW * 128;

#pragma unroll
  for (int s = 0; s < 4; ++s) {
    bf16x8 vfr[4], afr[4];
#pragma unroll
    for (int mf = 0; mf < 4; ++mf) {
      const int c = c0 + wr * 64 + mf * 16 + lr;
      vfr[mf] = *(const bf16x8*)(
          vbf + (size_t)c * kL + (size_t)h * kW + s * 32 + lg * 8);
    }
#pragma unroll
    for (int nf = 0; nf < 4; ++nf) {
      const int w = wc * 64 + nf * 16 + lr;
      afr[nf] = *(const bf16x8*)(arbase + (size_t)w * 128 + s * 32 + lg * 8);
    }
#pragma unroll
    for (int mf = 0; mf < 4; ++mf)
#pragma unroll
      for (int nf = 0; nf < 4; ++nf)
        acc[mf][nf] = __builtin_amdgcn_mfma_f32_16x16x32_bf16(
            vfr[mf], afr[nf], acc[mf][nf], 0, 0, 0);
  }

  const int wq = t & 31;
  const int cc8 = t >> 5;
  const unsigned short* ctb = ctmp + (size_t)h * kW;
  float* outb = out + ((size_t)b * kC * kL + (size_t)h * kW);
  for (int half = 0; half < 2; ++half) {
    if (wr == half) {
#pragma unroll
      for (int mf = 0; mf < 4; ++mf)
#pragma unroll
        for (int nf = 0; nf < 4; ++nf)
#pragma unroll
          for (int r = 0; r < 4; ++r)
            sO[(mf * 16 + lg * 4 + r) * ROW_SW + wc * 64 + nf * 16 + lr] =
                acc[mf][nf][r];
    }
    __syncthreads();
#pragma unroll
    for (int i = 0; i < 8; ++i) {
      const int cl = i * 8 + cc8;
      const size_t c = c0 + half * 64 + cl;
      float4 v = *(const float4*)&sO[cl * ROW_SW + wq * 4];
      uint2 c2 = *(const uint2*)(ctb + c * kL + wq * 4);
      v.x += bf16_to_f32((unsigned short)(c2.x & 0xffff));
      v.y += bf16_to_f32((unsigned short)(c2.x >> 16));
      v.z += bf16_to_f32((unsigned short)(c2.y & 0xffff));
      v.w += bf16_to_f32((unsigned short)(c2.y >> 16));
      *(float4*)(outb + c * kL + wq * 4) = v;
    }
    __syncthreads();
  }
}

extern "C" void kernel_launch(void* const* d_in, const int* in_sizes, int n_in,
                              void* d_out, int out_size, void* d_ws, size_t ws_size,
                              hipStream_t stream) {
  (void)in_sizes; (void)n_in; (void)out_size;
  const float* x  = (const float*)d_in[0];
  const float* Wq = (const float*)d_in[1];
  const float* bq = (const float*)d_in[2];
  const float* Wk = (const float*)d_in[3];
  const float* bk = (const float*)d_in[4];
  const float* Wv = (const float*)d_in[5];
  const float* bv = (const float*)d_in[6];
  float* out = (float*)d_out;
  float* ws  = (float*)d_ws;

  short* wpk = (short*)(ws + OFF_WALL);
  float* ball = ws + OFF_BALL;
  float* qkv  = ws + OFF_QKV;
  float* e    = ws + OFF_E;
  unsigned short* vfrag = (unsigned short*)(ws + OFF_E);

  pack_w<<<dim3(kO), dim3(256), 0, stream>>>(Wq, bq, Wk, bk, Wv, bv, wpk, ball);

  const size_t xpk_batch = (size_t)2 * kL * kC;
  const size_t need = WS_FLOATS * sizeof(float)
      + (size_t)kB * xpk_batch * sizeof(short);
  if (ws_size >= need) {
    short* xall = (short*)(ws + WS_FLOATS);
    pack_x<<<dim3(kL / 64, kC / 64, kB), dim3(256), 0, stream>>>(
        x, xall, 0, xpk_batch);
    proj_qk_mfma<<<dim3(512), dim3(256), 0, stream>>>(
        xall, xpk_batch, wpk, ball, qkv, 0, 64);
    proj_v_mfma<<<dim3(2048), dim3(256), 0, stream>>>(
        xall, xpk_batch, wpk, ball, qkv, 0, 64);
  } else {
    short* xpk = (short*)(ws + OFF_E);
    for (int b = 0; b < kB; ++b) {
      pack_x<<<dim3(kL / 64, kC / 64, 1), dim3(256), 0, stream>>>(x, xpk, b, 0);
      proj_qk_mfma<<<dim3(128), dim3(256), 0, stream>>>(
          xpk, 0, wpk, ball, qkv, b, 16);
      proj_v_mfma<<<dim3(512), dim3(256), 0, stream>>>(
          xpk, 0, wpk, ball, qkv, b, 16);
    }
  }

  qktrans_kernel<<<dim3(kH, kB), dim3(256), 0, stream>>>(qkv);

  unsigned short* qkb0 = (unsigned short*)qkv;
  escore_mfma<0><<<dim3(kB * kH), dim3(256), 0, stream>>>(
      qkb0 + QH_OFF, qkb0 + QL_OFF, qkb0 + KH_OFF, qkb0 + KL_OFF, e);
  unsigned short* vt0 = (unsigned short*)qkv + (size_t)128 * kL * 2 + CTMP_OFF;
  escore_mfma<1><<<dim3(kB * kW), dim3(256), 0, stream>>>(
      vt0 + 0, vt0 + 1048576, vt0 + 2097152, vt0 + 3145728, e);
  softmax_kernel<<<dim3(kB * kH * kW / 4), dim3(256), 0, stream>>>(e, qkv);
  vtrans_kernel<<<dim3(32, 8, kB), dim3(256), 0, stream>>>(qkv, vfrag);
  colagg_mfma<<<dim3(16, kW / 16, kB), dim3(1024), 0, stream>>>(qkv, vfrag);
  rowagg_mfma<<<dim3(4, kB * kH), dim3(256), 0, stream>>>(qkv, out);
}